// Round 6
// baseline (393.027 us; speedup 1.0000x reference)
//
#include <hip/hip_runtime.h>
#include <math.h>
#include <stdint.h>

#define NIMG   8
#define NA     30000      // H*W*A = 100*100*3
#define PRE_N  2000
#define POST_N 1000
#define NMS_TH 0.7f
#define DCLIP  4.135166556742356f   // log(1000/16)
#define IMGF   1600.0f
#define IMGM1  1599.0f
#define CAND_MAX 4096

// ws layout (floats): boxes [8][2000][4] @0, scores [8][2000] @64000,
//                     valid(int) [8][2000] @80000,
//                     mask(u64)  [8][2000][32] @96000 floats (byte 384000)

// ---------------------------------------------------------------------------
// Kernel 1: per-image top-2000 (by logit desc, idx asc), decode, clip, valid.
// R6: bitonic sorts replaced by rank-by-counting (C~2005 candidates, each
// thread counts #smaller keys via LDS broadcast loop, scatters to rank);
// barrier-scan replaced by wave-shuffle suffix scan.
// ---------------------------------------------------------------------------
__global__ __launch_bounds__(1024) void topk_decode(
    const float* __restrict__ obj,    // [8][3][100][100]
    const float* __restrict__ breg,   // [8][12][100][100]
    float* __restrict__ wsBoxes, float* __restrict__ wsScores,
    int* __restrict__ wsValid)
{
    const int n    = blockIdx.x;
    const int tid  = threadIdx.x;
    const int lane = tid & 63;
    const int wid  = tid >> 6;

    __shared__ uint64_t cbuf[CAND_MAX];   // 32 KB (aliases hist)
    __shared__ uint64_t sorted[PRE_N];    // 16 KB
    __shared__ unsigned int wsum[16];
    __shared__ unsigned int scal[4];

    unsigned int* hist = (unsigned int*)cbuf;  // 4096 bins, dead before cbuf use

    for (int b = tid; b < 4096; b += 1024) hist[b] = 0u;
    if (tid < 4) scal[tid] = 0u;
    __syncthreads();

    const float* objn = obj + n * NA;

    // pass 1: histogram over top-12 bits of sortable key
    for (int j = tid; j < NA; j += 1024) {
        unsigned int u = __float_as_uint(objn[j]);
        unsigned int k = (u & 0x80000000u) ? ~u : (u | 0x80000000u);
        atomicAdd(&hist[k >> 20], 1u);
    }
    __syncthreads();

    // suffix sums via wave shuffles to find boundary bin b*
    unsigned int c0 = hist[tid*4+0], c1 = hist[tid*4+1],
                 c2 = hist[tid*4+2], c3 = hist[tid*4+3];
    unsigned int p = c0 + c1 + c2 + c3;
    unsigned int s = p;
    #pragma unroll
    for (int off = 1; off < 64; off <<= 1) {
        unsigned int v = __shfl_down(s, off);
        if (lane + off < 64) s += v;
    }
    if (lane == 0) wsum[wid] = s;
    __syncthreads();
    unsigned int wafter = 0;
    for (int w = wid + 1; w < 16; ++w) wafter += wsum[w];
    unsigned int after = (s - p) + wafter;   // suffix-exclusive over my 4 bins
    {
        unsigned int S3 = after + c3;
        unsigned int S2 = S3 + c2;
        unsigned int S1 = S2 + c1;
        unsigned int S0 = S1 + c0;
        if (S3 >= PRE_N && after < PRE_N) { scal[2] = tid*4+3; }
        if (S2 >= PRE_N && S3    < PRE_N) { scal[2] = tid*4+2; }
        if (S1 >= PRE_N && S2    < PRE_N) { scal[2] = tid*4+1; }
        if (S0 >= PRE_N && S1    < PRE_N) { scal[2] = tid*4+0; }
    }
    __syncthreads();
    const unsigned int bstar = scal[2];

    // pass 2: collect ALL candidates (bin >= b*), unsorted
    for (int j = tid; j < NA; j += 1024) {
        unsigned int u = __float_as_uint(objn[j]);
        unsigned int k = (u & 0x80000000u) ? ~u : (u | 0x80000000u);
        if ((k >> 20) < bstar) continue;
        int a = j / 10000, t = j - a * 10000;
        uint64_t key = (((uint64_t)(~k)) << 32) | (unsigned int)(t * 3 + a);
        unsigned int pos = atomicAdd(&scal[0], 1u);
        if (pos < CAND_MAX) cbuf[pos] = key;
    }
    __syncthreads();
    const unsigned int C = min(scal[0], (unsigned int)CAND_MAX);

    // rank-by-counting: rank = #{j : key_j < key_mine}; top-2000 fill sorted[]
    uint64_t k0 = (tid < C) ? cbuf[tid] : 0ull;
    uint64_t k1 = (tid + 1024 < C) ? cbuf[tid + 1024] : 0ull;
    unsigned int r0 = 0, r1 = 0;
    if (C <= 2048u) {
        #pragma unroll 4
        for (unsigned int j = 0; j < C; ++j) {
            uint64_t kj = cbuf[j];
            r0 += (kj < k0); r1 += (kj < k1);
        }
        if (tid < C && r0 < PRE_N) sorted[r0] = k0;
        if (tid + 1024 < C && r1 < PRE_N) sorted[r1] = k1;
    } else {
        uint64_t k2 = (tid + 2048 < C) ? cbuf[tid + 2048] : 0ull;
        uint64_t k3 = (tid + 3072 < C) ? cbuf[tid + 3072] : 0ull;
        unsigned int r2 = 0, r3 = 0;
        #pragma unroll 4
        for (unsigned int j = 0; j < C; ++j) {
            uint64_t kj = cbuf[j];
            r0 += (kj < k0); r1 += (kj < k1); r2 += (kj < k2); r3 += (kj < k3);
        }
        if (tid < C && r0 < PRE_N) sorted[r0] = k0;
        if (tid + 1024 < C && r1 < PRE_N) sorted[r1] = k1;
        if (tid + 2048 < C && r2 < PRE_N) sorted[r2] = k2;
        if (tid + 3072 < C && r3 < PRE_N) sorted[r3] = k3;
    }
    __syncthreads();

    // decode + clip + valid (unchanged math — verified bit-exact)
    for (int r = tid; r < PRE_N; r += 1024) {
        uint64_t key = sorted[r];
        unsigned int idx = (unsigned int)key;
        unsigned int k   = ~((unsigned int)(key >> 32));
        unsigned int u   = (k & 0x80000000u) ? (k & 0x7fffffffu) : ~k;
        float logit = __uint_as_float(u);
        float score = 1.0f / (1.0f + expf(-logit));

        int a = idx % 3, t = idx / 3, w = t % 100, h = t / 100;
        const float* bp = breg + n*120000 + (a*4)*10000 + t;
        float dx = bp[0], dy = bp[10000], dw = bp[20000], dh = bp[30000];

        float half = (a == 0) ? 32.0f : ((a == 1) ? 64.0f : 128.0f);
        float cx = w * 16.0f + 8.0f, cy = h * 16.0f + 8.0f;
        float x1 = cx - half, y1 = cy - half, x2 = cx + half, y2 = cy + half;
        float wd = x2 - x1 + 1.0f, hg = y2 - y1 + 1.0f;
        float cxr = x1 + 0.5f * wd, cyr = y1 + 0.5f * hg;
        dw = fminf(dw, DCLIP); dh = fminf(dh, DCLIP);
        float pcx = dx * wd + cxr, pcy = dy * hg + cyr;
        float pw = expf(dw) * wd, ph = expf(dh) * hg;
        float px1 = pcx - 0.5f * pw, py1 = pcy - 0.5f * ph;
        float px2 = pcx + 0.5f * pw - 1.0f, py2 = pcy + 0.5f * ph - 1.0f;
        px1 = fminf(fmaxf(px1, 0.0f), IMGM1);
        px2 = fminf(fmaxf(px2, 0.0f), IMGM1);
        py1 = fminf(fmaxf(py1, 0.0f), IMGM1);
        py2 = fminf(fmaxf(py2, 0.0f), IMGM1);
        float wss = px2 - px1 + 1.0f, hss = py2 - py1 + 1.0f;
        float xc = px1 + wss * 0.5f, yc = py1 + hss * 0.5f;
        int valid = (wss >= 0.0f) && (hss >= 0.0f) && (xc < IMGF) && (yc < IMGF);

        float4 bx = make_float4(px1, py1, px2, py2);
        ((float4*)wsBoxes)[n * PRE_N + r] = bx;
        wsScores[n * PRE_N + r] = score;
        wsValid [n * PRE_N + r] = valid;
    }
}

// ---------------------------------------------------------------------------
// Kernel 2 (R6): lanes = columns, so a row's 64 IoU bits ARE a __ballot().
// Column boxes in registers (coalesced float4/lane); row box broadcast from
// tiny LDS. One u64 store per (row, word). Lower triangle is zero via the
// hipMemsetAsync in kernel_launch.
// ---------------------------------------------------------------------------
__global__ __launch_bounds__(256) void nms_mask(
    const float* __restrict__ wsBoxes, uint64_t* __restrict__ mask)
{
    const int blk  = blockIdx.x;
    const int n    = blk >> 5;
    const int i_t  = blk & 31;
    const int tid  = threadIdx.x;
    const int lane = tid & 63;
    const int wv   = tid >> 6;   // 0..3

    __shared__ float4 rbox[64];
    __shared__ float  rarea[64];

    if (tid < 64) {
        int r = i_t * 64 + tid;
        float4 b = (r < PRE_N) ? ((const float4*)wsBoxes)[n * PRE_N + r]
                               : make_float4(0.f, 0.f, 0.f, 0.f);
        rbox[tid]  = b;
        rarea[tid] = (b.z - b.x + 1.0f) * (b.w - b.y + 1.0f);
    }
    __syncthreads();

    uint64_t* mrow = mask + ((size_t)n * PRE_N + (size_t)i_t * 64) * 32;
    const int cmax = (i_t == 31) ? 16 : 64;    // rows >= 2000 don't exist

    for (int j_t = i_t + wv; j_t < 32; j_t += 4) {
        const int j = j_t * 64 + lane;
        float4 cb = (j < PRE_N) ? ((const float4*)wsBoxes)[n * PRE_N + j]
                                : make_float4(3e30f, 3e30f, 3e30f, 3e30f);
        float ca = (cb.z - cb.x + 1.0f) * (cb.w - cb.y + 1.0f);
        const uint64_t jmask = (j_t == 31) ? 0xFFFFull : ~0ull;
        const bool diag = (j_t == i_t);

        for (int c = 0; c < cmax; ++c) {
            float4 rb = rbox[c];
            float  ar = rarea[c];
            float xx1 = fmaxf(rb.x, cb.x), yy1 = fmaxf(rb.y, cb.y);
            float xx2 = fminf(rb.z, cb.z), yy2 = fminf(rb.w, cb.w);
            float ww = fmaxf(xx2 - xx1 + 1.0f, 0.0f);
            float hh = fmaxf(yy2 - yy1 + 1.0f, 0.0f);
            float inter = ww * hh;
            float iou = inter / (ar + ca - inter);
            unsigned long long bits = __ballot(iou > NMS_TH);
            bits &= jmask;
            if (diag) bits &= (c == 63) ? 0ull : ((~0ull) << (c + 1));
            if (lane == 0) mrow[(size_t)c * 32 + j_t] = bits;
        }
    }
}

// ---------------------------------------------------------------------------
// Kernel 3 (R6): serial greedy scan, inline asm. 64-slot physical-VGPR ring
// (v64..v127 via clobbers) of global_load_dword pinned with vmcnt(63);
// current 32-row window kept in an SGPR (s_bitcmp1 test -> 1 readlane/row);
// early-exit once kept==1000 (provably output-identical). Lane l owns u32
// word l of the 2048-bit removed vector.
// ---------------------------------------------------------------------------
#define SL(n,b) \
    "global_load_dword v" #n ", %[voff], %[sbase]\n\t" \
    "v_add_u32 %[voff], 0x100, %[voff]\n\t"

#define SS(n,b) \
    "s_waitcnt vmcnt(63)\n\t" \
    "s_bitcmp1_b32 %[win], " #b "\n\t" \
    "s_cselect_b32 %[m], 0, -1\n\t" \
    "s_sub_i32 %[kept], %[kept], %[m]\n\t" \
    "v_and_b32 v" #n ", %[m], v" #n "\n\t" \
    "v_or_b32 %[rem], %[rem], v" #n "\n\t" \
    "v_readlane_b32 %[t], v" #n ", %[lw]\n\t" \
    "s_or_b32 %[win], %[win], %[t]\n\t" \
    "global_load_dword v" #n ", %[voff], %[sbase]\n\t" \
    "v_add_u32 %[voff], 0x100, %[voff]\n\t"

#define SN(n,b,w) \
    "s_waitcnt vmcnt(" #w ")\n\t" \
    "s_bitcmp1_b32 %[win], " #b "\n\t" \
    "s_cselect_b32 %[m], 0, -1\n\t" \
    "s_sub_i32 %[kept], %[kept], %[m]\n\t" \
    "v_and_b32 v" #n ", %[m], v" #n "\n\t" \
    "v_or_b32 %[rem], %[rem], v" #n "\n\t" \
    "v_readlane_b32 %[t], v" #n ", %[lw]\n\t" \
    "s_or_b32 %[win], %[win], %[t]\n\t"

#define SWIN \
    "s_add_u32 %[lw], %[lw], 1\n\t" \
    "v_readlane_b32 %[t], %[rem], %[lw]\n\t" \
    "s_mov_b32 %[win], %[t]\n\t"

#define ROW_A(M) M(64,0) M(65,1) M(66,2) M(67,3) M(68,4) M(69,5) M(70,6) M(71,7) \
    M(72,8) M(73,9) M(74,10) M(75,11) M(76,12) M(77,13) M(78,14) M(79,15) \
    M(80,16) M(81,17) M(82,18) M(83,19) M(84,20) M(85,21) M(86,22) M(87,23) \
    M(88,24) M(89,25) M(90,26) M(91,27) M(92,28) M(93,29) M(94,30) M(95,31)
#define ROW_B(M) M(96,0) M(97,1) M(98,2) M(99,3) M(100,4) M(101,5) M(102,6) M(103,7) \
    M(104,8) M(105,9) M(106,10) M(107,11) M(108,12) M(109,13) M(110,14) M(111,15) \
    M(112,16) M(113,17) M(114,18) M(115,19) M(116,20) M(117,21) M(118,22) M(119,23) \
    M(120,24) M(121,25) M(122,26) M(123,27) M(124,28) M(125,29) M(126,30) M(127,31)

__global__ __launch_bounds__(256) void nms_scan_select(
    const float* __restrict__ wsBoxes, const float* __restrict__ wsScores,
    const int* __restrict__ wsValid, const uint64_t* __restrict__ mask,
    float* __restrict__ out)
{
    const int n   = blockIdx.x;
    const int tid = threadIdx.x;

    __shared__ __align__(8) unsigned char invb[256];
    __shared__ unsigned int keepw32[64];
    __shared__ int sscan[256];

    // initially-removed bits: !valid for rows < 2000, forced-removed padding
    unsigned int byte = 0xFFu;
    if (tid < PRE_N / 8) {
        byte = 0u;
        for (int q = 0; q < 8; ++q)
            byte |= (wsValid[n * PRE_N + tid * 8 + q] ? 0u : 1u) << q;
    }
    invb[tid] = (unsigned char)byte;
    __syncthreads();

    if (tid < 64) {
        unsigned int rem = ((const unsigned int*)invb)[tid];
        unsigned long long sbase =
            (unsigned long long)(const void*)(mask + (size_t)n * PRE_N * 32);
        unsigned int voff = (unsigned int)(tid * 4);
        int win_, m_, t_, lw_, kept_, cnt_;

        asm volatile(
            "s_waitcnt vmcnt(0) lgkmcnt(0)\n\t"
            "s_mov_b32 %[kept], 0\n\t"
            "s_mov_b32 %[lw], 0\n\t"
            ROW_A(SL) ROW_B(SL)            // preload rows 0..63
            "v_readlane_b32 %[t], %[rem], %[lw]\n\t"
            "s_mov_b32 %[win], %[t]\n\t"
            "s_mov_b32 %[cnt], 30\n\t"
            "Lnms_%=:\n\t"                 // 30 iters: rows 0..1919, loads ..1983
            ROW_A(SS)
            SWIN
            ROW_B(SS)
            SWIN
            "s_cmp_ge_i32 %[kept], 0x3e8\n\t"
            "s_cbranch_scc1 Lend_%=\n\t"
            "s_sub_u32 %[cnt], %[cnt], 1\n\t"
            "s_cmp_lg_u32 %[cnt], 0\n\t"
            "s_cbranch_scc1 Lnms_%=\n\t"
            // mixed iter: rows 1920..1983; steps 0..15 also load rows 1984..1999
            SS(64,0) SS(65,1) SS(66,2) SS(67,3) SS(68,4) SS(69,5) SS(70,6) SS(71,7)
            SS(72,8) SS(73,9) SS(74,10) SS(75,11) SS(76,12) SS(77,13) SS(78,14) SS(79,15)
            SN(80,16,63) SN(81,17,62) SN(82,18,61) SN(83,19,60)
            SN(84,20,59) SN(85,21,58) SN(86,22,57) SN(87,23,56)
            SN(88,24,55) SN(89,25,54) SN(90,26,53) SN(91,27,52)
            SN(92,28,51) SN(93,29,50) SN(94,30,49) SN(95,31,48)
            SWIN
            SN(96,0,47) SN(97,1,46) SN(98,2,45) SN(99,3,44)
            SN(100,4,43) SN(101,5,42) SN(102,6,41) SN(103,7,40)
            SN(104,8,39) SN(105,9,38) SN(106,10,37) SN(107,11,36)
            SN(108,12,35) SN(109,13,34) SN(110,14,33) SN(111,15,32)
            SN(112,16,31) SN(113,17,30) SN(114,18,29) SN(115,19,28)
            SN(116,20,27) SN(117,21,26) SN(118,22,25) SN(119,23,24)
            SN(120,24,23) SN(121,25,22) SN(122,26,21) SN(123,27,20)
            SN(124,28,19) SN(125,29,18) SN(126,30,17) SN(127,31,16)
            SWIN
            // final: rows 1984..1999 in slots v64..v79
            SN(64,0,15) SN(65,1,14) SN(66,2,13) SN(67,3,12)
            SN(68,4,11) SN(69,5,10) SN(70,6,9) SN(71,7,8)
            SN(72,8,7) SN(73,9,6) SN(74,10,5) SN(75,11,4)
            SN(76,12,3) SN(77,13,2) SN(78,14,1) SN(79,15,0)
            "Lend_%=:\n\t"
            "s_waitcnt vmcnt(0)\n\t"
            : [rem]"+v"(rem), [voff]"+v"(voff),
              [win]"=&s"(win_), [m]"=&s"(m_), [t]"=&s"(t_),
              [lw]"=&s"(lw_), [kept]"=&s"(kept_), [cnt]"=&s"(cnt_)
            : [sbase]"s"(sbase)
            : "scc", "vcc", "memory",
              "v64","v65","v66","v67","v68","v69","v70","v71",
              "v72","v73","v74","v75","v76","v77","v78","v79",
              "v80","v81","v82","v83","v84","v85","v86","v87",
              "v88","v89","v90","v91","v92","v93","v94","v95",
              "v96","v97","v98","v99","v100","v101","v102","v103",
              "v104","v105","v106","v107","v108","v109","v110","v111",
              "v112","v113","v114","v115","v116","v117","v118","v119",
              "v120","v121","v122","v123","v124","v125","v126","v127");

        keepw32[tid] = ~rem;   // padding rows auto-dead via invb=0xFF
    }
    __syncthreads();

    // prefix scan of keep flags, 8 per thread
    int c[8]; const int base8 = tid * 8;
    int lsum = 0;
    for (int q = 0; q < 8; ++q) {
        const int i = base8 + q;
        c[q] = (i < PRE_N) ? (int)((keepw32[i >> 5] >> (i & 31)) & 1u) : 0;
        lsum += c[q];
    }
    sscan[tid] = lsum;
    __syncthreads();
    for (int off = 1; off < 256; off <<= 1) {
        int v = (tid >= off) ? sscan[tid - off] : 0;
        __syncthreads();
        sscan[tid] += v;
        __syncthreads();
    }
    const int excl  = sscan[tid] - lsum;
    const int total = sscan[255];

    float* ob  = out + n * POST_N * 4;
    float* osc = out + NIMG * POST_N * 4 + n * POST_N;
    float* ovd = out + NIMG * POST_N * 5 + n * POST_N;

    for (int i = tid; i < POST_N * 4; i += 256) ob[i] = 0.0f;
    for (int i = tid; i < POST_N; i += 256) osc[i] = 0.0f;
    const int lim = min(total, POST_N);
    for (int i = tid; i < POST_N; i += 256) ovd[i] = (i < lim) ? 1.0f : 0.0f;
    __syncthreads();

    int run = excl;
    for (int q = 0; q < 8; ++q) {
        const int i = base8 + q;
        if (i < PRE_N && c[q]) {
            if (run < POST_N) {
                float4 b = ((const float4*)wsBoxes)[n * PRE_N + i];
                ob[run * 4 + 0] = b.x;
                ob[run * 4 + 1] = b.y;
                ob[run * 4 + 2] = b.z;
                ob[run * 4 + 3] = b.w;
                osc[run] = wsScores[n * PRE_N + i];
            }
            run++;
        }
    }
}

extern "C" void kernel_launch(void* const* d_in, const int* in_sizes, int n_in,
                              void* d_out, int out_size, void* d_ws, size_t ws_size,
                              hipStream_t stream) {
    const float* obj  = (const float*)d_in[0];
    const float* breg = (const float*)d_in[1];
    // d_in[2] anchors unused (computed inline, exact in f32)
    float* ws        = (float*)d_ws;
    float* wsBoxes   = ws;                      // 64000 floats
    float* wsScores  = ws + 64000;              // 16000 floats
    int*   wsValid   = (int*)(ws + 80000);      // 16000 ints
    uint64_t* wsMask = (uint64_t*)(ws + 96000); // 8*2000*32 u64 = 4 MB

    hipMemsetAsync(wsMask, 0, (size_t)NIMG * PRE_N * 32 * sizeof(uint64_t), stream);
    topk_decode<<<NIMG, 1024, 0, stream>>>(obj, breg, wsBoxes, wsScores, wsValid);
    nms_mask<<<NIMG * 32, 256, 0, stream>>>(wsBoxes, wsMask);
    nms_scan_select<<<NIMG, 256, 0, stream>>>(wsBoxes, wsScores, wsValid, wsMask,
                                              (float*)d_out);
}

// Round 7
// 255.760 us; speedup vs baseline: 1.5367x; 1.5367x over previous
//
#include <hip/hip_runtime.h>
#include <math.h>
#include <stdint.h>

#define NIMG   8
#define NA     30000      // H*W*A = 100*100*3
#define PRE_N  2000
#define POST_N 1000
#define NMS_TH 0.7f
#define DCLIP  4.135166556742356f   // log(1000/16)
#define IMGF   1600.0f
#define IMGM1  1599.0f
#define CAND_MAX 4096

// ws layout (floats): boxes [8][2000][4] @0, scores [8][2000] @64000,
//   valid(int) [8][2000] @80000, mask(u64) [8][2000][32] @96000.
// candBuf (u64 [8][4096]) + candCnt alias the START of the mask region:
// they are produced by hist_compact, consumed by rank_decode, and only then
// does nms_mask overwrite the region (same stream => safe).

// ---------------------------------------------------------------------------
// Kernel A: per-image 12-bit histogram over sortable keys, boundary bin b*,
// compact ALL candidates (bin >= b*) unsorted to global candBuf.
// ---------------------------------------------------------------------------
__global__ __launch_bounds__(1024) void hist_compact(
    const float* __restrict__ obj,     // [8][3][100][100]
    uint64_t* __restrict__ candBuf, unsigned int* __restrict__ candCnt)
{
    const int n    = blockIdx.x;
    const int tid  = threadIdx.x;
    const int lane = tid & 63;
    const int wid  = tid >> 6;

    __shared__ unsigned int hist[4096];
    __shared__ unsigned int wsum[16];
    __shared__ unsigned int scal[4];

    for (int b = tid; b < 4096; b += 1024) hist[b] = 0u;
    if (tid < 4) scal[tid] = 0u;
    __syncthreads();

    const float* objn = obj + n * NA;

    for (int j = tid; j < NA; j += 1024) {
        unsigned int u = __float_as_uint(objn[j]);
        unsigned int k = (u & 0x80000000u) ? ~u : (u | 0x80000000u);
        atomicAdd(&hist[k >> 20], 1u);
    }
    __syncthreads();

    // suffix sums via wave shuffles to find boundary bin b*  (verified R6)
    unsigned int c0 = hist[tid*4+0], c1 = hist[tid*4+1],
                 c2 = hist[tid*4+2], c3 = hist[tid*4+3];
    unsigned int p = c0 + c1 + c2 + c3;
    unsigned int s = p;
    #pragma unroll
    for (int off = 1; off < 64; off <<= 1) {
        unsigned int v = __shfl_down(s, off);
        if (lane + off < 64) s += v;
    }
    if (lane == 0) wsum[wid] = s;
    __syncthreads();
    unsigned int wafter = 0;
    for (int w = wid + 1; w < 16; ++w) wafter += wsum[w];
    unsigned int after = (s - p) + wafter;
    {
        unsigned int S3 = after + c3;
        unsigned int S2 = S3 + c2;
        unsigned int S1 = S2 + c1;
        unsigned int S0 = S1 + c0;
        if (S3 >= PRE_N && after < PRE_N) { scal[2] = tid*4+3; }
        if (S2 >= PRE_N && S3    < PRE_N) { scal[2] = tid*4+2; }
        if (S1 >= PRE_N && S2    < PRE_N) { scal[2] = tid*4+1; }
        if (S0 >= PRE_N && S1    < PRE_N) { scal[2] = tid*4+0; }
    }
    __syncthreads();
    const unsigned int bstar = scal[2];

    // compact all candidates (bin >= b*), unsorted, to global
    for (int j = tid; j < NA; j += 1024) {
        unsigned int u = __float_as_uint(objn[j]);
        unsigned int k = (u & 0x80000000u) ? ~u : (u | 0x80000000u);
        if ((k >> 20) < bstar) continue;
        int a = j / 10000, t = j - a * 10000;
        uint64_t key = (((uint64_t)(~k)) << 32) | (unsigned int)(t * 3 + a);
        unsigned int pos = atomicAdd(&scal[0], 1u);
        if (pos < CAND_MAX) candBuf[n * CAND_MAX + pos] = key;
    }
    __syncthreads();
    if (tid == 0) candCnt[n] = min(scal[0], (unsigned int)CAND_MAX);
}

// ---------------------------------------------------------------------------
// Kernel B: massively parallel rank-by-counting + decode. 32 tiles x 128 thr
// per image; each thread owns ONE candidate, ranks it against all C keys in
// LDS (broadcast reads), and if rank < 2000 decodes & writes box/score/valid
// directly to slot `rank`. Keys are unique => ranks are a permutation.
// ---------------------------------------------------------------------------
__global__ __launch_bounds__(128) void rank_decode(
    const float* __restrict__ breg,    // [8][12][100][100]
    const uint64_t* __restrict__ candBuf, const unsigned int* __restrict__ candCnt,
    float* __restrict__ wsBoxes, float* __restrict__ wsScores,
    int* __restrict__ wsValid)
{
    const int n    = blockIdx.x >> 5;   // 32 tiles per image
    const int tile = blockIdx.x & 31;
    const int tid  = threadIdx.x;

    __shared__ uint64_t keys[CAND_MAX];   // 32 KB

    const int C = (int)candCnt[n];
    if (tile * 128 >= C) return;          // uniform: whole block idle

    for (int i = tid; i < C; i += 128) keys[i] = candBuf[n * CAND_MAX + i];
    __syncthreads();

    const int my = tile * 128 + tid;
    if (my >= C) return;
    const uint64_t km = keys[my];
    unsigned int rank = 0;
    for (int j = 0; j < C; ++j) rank += (keys[j] < km);
    if (rank >= PRE_N) return;

    // decode + clip + valid (bit-exact math, verified R1-R6)
    unsigned int idx = (unsigned int)km;
    unsigned int k   = ~((unsigned int)(km >> 32));
    unsigned int u   = (k & 0x80000000u) ? (k & 0x7fffffffu) : ~k;
    float logit = __uint_as_float(u);
    float score = 1.0f / (1.0f + expf(-logit));

    int a = idx % 3, t = idx / 3, w = t % 100, h = t / 100;
    const float* bp = breg + n*120000 + (a*4)*10000 + t;
    float dx = bp[0], dy = bp[10000], dw = bp[20000], dh = bp[30000];

    float half = (a == 0) ? 32.0f : ((a == 1) ? 64.0f : 128.0f);
    float cx = w * 16.0f + 8.0f, cy = h * 16.0f + 8.0f;
    float x1 = cx - half, y1 = cy - half, x2 = cx + half, y2 = cy + half;
    float wd = x2 - x1 + 1.0f, hg = y2 - y1 + 1.0f;
    float cxr = x1 + 0.5f * wd, cyr = y1 + 0.5f * hg;
    dw = fminf(dw, DCLIP); dh = fminf(dh, DCLIP);
    float pcx = dx * wd + cxr, pcy = dy * hg + cyr;
    float pw = expf(dw) * wd, ph = expf(dh) * hg;
    float px1 = pcx - 0.5f * pw, py1 = pcy - 0.5f * ph;
    float px2 = pcx + 0.5f * pw - 1.0f, py2 = pcy + 0.5f * ph - 1.0f;
    px1 = fminf(fmaxf(px1, 0.0f), IMGM1);
    px2 = fminf(fmaxf(px2, 0.0f), IMGM1);
    py1 = fminf(fmaxf(py1, 0.0f), IMGM1);
    py2 = fminf(fmaxf(py2, 0.0f), IMGM1);
    float wss = px2 - px1 + 1.0f, hss = py2 - py1 + 1.0f;
    float xc = px1 + wss * 0.5f, yc = py1 + hss * 0.5f;
    int valid = (wss >= 0.0f) && (hss >= 0.0f) && (xc < IMGF) && (yc < IMGF);

    ((float4*)wsBoxes)[n * PRE_N + (int)rank] = make_float4(px1, py1, px2, py2);
    wsScores[n * PRE_N + (int)rank] = score;
    wsValid [n * PRE_N + (int)rank] = valid;
}

// ---------------------------------------------------------------------------
// Kernel C: suppression bit-matrix, lanes = columns (ballot per row). Also
// zero-fills its own lower-triangle words (replaces the 4 MB memset launch).
// ---------------------------------------------------------------------------
__global__ __launch_bounds__(256) void nms_mask(
    const float* __restrict__ wsBoxes, uint64_t* __restrict__ mask)
{
    const int blk  = blockIdx.x;
    const int n    = blk >> 5;
    const int i_t  = blk & 31;
    const int tid  = threadIdx.x;
    const int lane = tid & 63;
    const int wv   = tid >> 6;   // 0..3

    __shared__ float4 rbox[64];
    __shared__ float  rarea[64];

    uint64_t* mrow = mask + ((size_t)n * PRE_N + (size_t)i_t * 64) * 32;
    const int cmax = (i_t == 31) ? 16 : 64;    // rows >= 2000 don't exist

    // zero lower-triangle words (j_t < i_t) for this block's live rows
    for (int r = wv; r < cmax; r += 4)
        for (int w = lane; w < i_t; w += 64)
            mrow[(size_t)r * 32 + w] = 0ull;

    if (tid < 64) {
        int r = i_t * 64 + tid;
        float4 b = (r < PRE_N) ? ((const float4*)wsBoxes)[n * PRE_N + r]
                               : make_float4(0.f, 0.f, 0.f, 0.f);
        rbox[tid]  = b;
        rarea[tid] = (b.z - b.x + 1.0f) * (b.w - b.y + 1.0f);
    }
    __syncthreads();

    for (int j_t = i_t + wv; j_t < 32; j_t += 4) {
        const int j = j_t * 64 + lane;
        float4 cb = (j < PRE_N) ? ((const float4*)wsBoxes)[n * PRE_N + j]
                                : make_float4(3e30f, 3e30f, 3e30f, 3e30f);
        float ca = (cb.z - cb.x + 1.0f) * (cb.w - cb.y + 1.0f);
        const uint64_t jmask = (j_t == 31) ? 0xFFFFull : ~0ull;
        const bool diag = (j_t == i_t);

        for (int c = 0; c < cmax; ++c) {
            float4 rb = rbox[c];
            float  ar = rarea[c];
            float xx1 = fmaxf(rb.x, cb.x), yy1 = fmaxf(rb.y, cb.y);
            float xx2 = fminf(rb.z, cb.z), yy2 = fminf(rb.w, cb.w);
            float ww = fmaxf(xx2 - xx1 + 1.0f, 0.0f);
            float hh = fmaxf(yy2 - yy1 + 1.0f, 0.0f);
            float inter = ww * hh;
            float iou = inter / (ar + ca - inter);
            unsigned long long bits = __ballot(iou > NMS_TH);
            bits &= jmask;
            if (diag) bits &= (c == 63) ? 0ull : ((~0ull) << (c + 1));
            if (lane == 0) mrow[(size_t)c * 32 + j_t] = bits;
        }
    }
}

// ---------------------------------------------------------------------------
// Kernel D (unchanged, verified R6): serial greedy scan, inline asm, 64-slot
// physical-VGPR ring pinned with vmcnt; SGPR window; early-exit at kept=1000.
// ---------------------------------------------------------------------------
#define SL(n,b) \
    "global_load_dword v" #n ", %[voff], %[sbase]\n\t" \
    "v_add_u32 %[voff], 0x100, %[voff]\n\t"

#define SS(n,b) \
    "s_waitcnt vmcnt(63)\n\t" \
    "s_bitcmp1_b32 %[win], " #b "\n\t" \
    "s_cselect_b32 %[m], 0, -1\n\t" \
    "s_sub_i32 %[kept], %[kept], %[m]\n\t" \
    "v_and_b32 v" #n ", %[m], v" #n "\n\t" \
    "v_or_b32 %[rem], %[rem], v" #n "\n\t" \
    "v_readlane_b32 %[t], v" #n ", %[lw]\n\t" \
    "s_or_b32 %[win], %[win], %[t]\n\t" \
    "global_load_dword v" #n ", %[voff], %[sbase]\n\t" \
    "v_add_u32 %[voff], 0x100, %[voff]\n\t"

#define SN(n,b,w) \
    "s_waitcnt vmcnt(" #w ")\n\t" \
    "s_bitcmp1_b32 %[win], " #b "\n\t" \
    "s_cselect_b32 %[m], 0, -1\n\t" \
    "s_sub_i32 %[kept], %[kept], %[m]\n\t" \
    "v_and_b32 v" #n ", %[m], v" #n "\n\t" \
    "v_or_b32 %[rem], %[rem], v" #n "\n\t" \
    "v_readlane_b32 %[t], v" #n ", %[lw]\n\t" \
    "s_or_b32 %[win], %[win], %[t]\n\t"

#define SWIN \
    "s_add_u32 %[lw], %[lw], 1\n\t" \
    "v_readlane_b32 %[t], %[rem], %[lw]\n\t" \
    "s_mov_b32 %[win], %[t]\n\t"

#define ROW_A(M) M(64,0) M(65,1) M(66,2) M(67,3) M(68,4) M(69,5) M(70,6) M(71,7) \
    M(72,8) M(73,9) M(74,10) M(75,11) M(76,12) M(77,13) M(78,14) M(79,15) \
    M(80,16) M(81,17) M(82,18) M(83,19) M(84,20) M(85,21) M(86,22) M(87,23) \
    M(88,24) M(89,25) M(90,26) M(91,27) M(92,28) M(93,29) M(94,30) M(95,31)
#define ROW_B(M) M(96,0) M(97,1) M(98,2) M(99,3) M(100,4) M(101,5) M(102,6) M(103,7) \
    M(104,8) M(105,9) M(106,10) M(107,11) M(108,12) M(109,13) M(110,14) M(111,15) \
    M(112,16) M(113,17) M(114,18) M(115,19) M(116,20) M(117,21) M(118,22) M(119,23) \
    M(120,24) M(121,25) M(122,26) M(123,27) M(124,28) M(125,29) M(126,30) M(127,31)

__global__ __launch_bounds__(256) void nms_scan_select(
    const float* __restrict__ wsBoxes, const float* __restrict__ wsScores,
    const int* __restrict__ wsValid, const uint64_t* __restrict__ mask,
    float* __restrict__ out)
{
    const int n   = blockIdx.x;
    const int tid = threadIdx.x;

    __shared__ __align__(8) unsigned char invb[256];
    __shared__ unsigned int keepw32[64];
    __shared__ int sscan[256];

    unsigned int byte = 0xFFu;
    if (tid < PRE_N / 8) {
        byte = 0u;
        for (int q = 0; q < 8; ++q)
            byte |= (wsValid[n * PRE_N + tid * 8 + q] ? 0u : 1u) << q;
    }
    invb[tid] = (unsigned char)byte;
    __syncthreads();

    if (tid < 64) {
        unsigned int rem = ((const unsigned int*)invb)[tid];
        unsigned long long sbase =
            (unsigned long long)(const void*)(mask + (size_t)n * PRE_N * 32);
        unsigned int voff = (unsigned int)(tid * 4);
        int win_, m_, t_, lw_, kept_, cnt_;

        asm volatile(
            "s_waitcnt vmcnt(0) lgkmcnt(0)\n\t"
            "s_mov_b32 %[kept], 0\n\t"
            "s_mov_b32 %[lw], 0\n\t"
            ROW_A(SL) ROW_B(SL)
            "v_readlane_b32 %[t], %[rem], %[lw]\n\t"
            "s_mov_b32 %[win], %[t]\n\t"
            "s_mov_b32 %[cnt], 30\n\t"
            "Lnms_%=:\n\t"
            ROW_A(SS)
            SWIN
            ROW_B(SS)
            SWIN
            "s_cmp_ge_i32 %[kept], 0x3e8\n\t"
            "s_cbranch_scc1 Lend_%=\n\t"
            "s_sub_u32 %[cnt], %[cnt], 1\n\t"
            "s_cmp_lg_u32 %[cnt], 0\n\t"
            "s_cbranch_scc1 Lnms_%=\n\t"
            SS(64,0) SS(65,1) SS(66,2) SS(67,3) SS(68,4) SS(69,5) SS(70,6) SS(71,7)
            SS(72,8) SS(73,9) SS(74,10) SS(75,11) SS(76,12) SS(77,13) SS(78,14) SS(79,15)
            SN(80,16,63) SN(81,17,62) SN(82,18,61) SN(83,19,60)
            SN(84,20,59) SN(85,21,58) SN(86,22,57) SN(87,23,56)
            SN(88,24,55) SN(89,25,54) SN(90,26,53) SN(91,27,52)
            SN(92,28,51) SN(93,29,50) SN(94,30,49) SN(95,31,48)
            SWIN
            SN(96,0,47) SN(97,1,46) SN(98,2,45) SN(99,3,44)
            SN(100,4,43) SN(101,5,42) SN(102,6,41) SN(103,7,40)
            SN(104,8,39) SN(105,9,38) SN(106,10,37) SN(107,11,36)
            SN(108,12,35) SN(109,13,34) SN(110,14,33) SN(111,15,32)
            SN(112,16,31) SN(113,17,30) SN(114,18,29) SN(115,19,28)
            SN(116,20,27) SN(117,21,26) SN(118,22,25) SN(119,23,24)
            SN(120,24,23) SN(121,25,22) SN(122,26,21) SN(123,27,20)
            SN(124,28,19) SN(125,29,18) SN(126,30,17) SN(127,31,16)
            SWIN
            SN(64,0,15) SN(65,1,14) SN(66,2,13) SN(67,3,12)
            SN(68,4,11) SN(69,5,10) SN(70,6,9) SN(71,7,8)
            SN(72,8,7) SN(73,9,6) SN(74,10,5) SN(75,11,4)
            SN(76,12,3) SN(77,13,2) SN(78,14,1) SN(79,15,0)
            "Lend_%=:\n\t"
            "s_waitcnt vmcnt(0)\n\t"
            : [rem]"+v"(rem), [voff]"+v"(voff),
              [win]"=&s"(win_), [m]"=&s"(m_), [t]"=&s"(t_),
              [lw]"=&s"(lw_), [kept]"=&s"(kept_), [cnt]"=&s"(cnt_)
            : [sbase]"s"(sbase)
            : "scc", "vcc", "memory",
              "v64","v65","v66","v67","v68","v69","v70","v71",
              "v72","v73","v74","v75","v76","v77","v78","v79",
              "v80","v81","v82","v83","v84","v85","v86","v87",
              "v88","v89","v90","v91","v92","v93","v94","v95",
              "v96","v97","v98","v99","v100","v101","v102","v103",
              "v104","v105","v106","v107","v108","v109","v110","v111",
              "v112","v113","v114","v115","v116","v117","v118","v119",
              "v120","v121","v122","v123","v124","v125","v126","v127");

        keepw32[tid] = ~rem;
    }
    __syncthreads();

    int c[8]; const int base8 = tid * 8;
    int lsum = 0;
    for (int q = 0; q < 8; ++q) {
        const int i = base8 + q;
        c[q] = (i < PRE_N) ? (int)((keepw32[i >> 5] >> (i & 31)) & 1u) : 0;
        lsum += c[q];
    }
    sscan[tid] = lsum;
    __syncthreads();
    for (int off = 1; off < 256; off <<= 1) {
        int v = (tid >= off) ? sscan[tid - off] : 0;
        __syncthreads();
        sscan[tid] += v;
        __syncthreads();
    }
    const int excl  = sscan[tid] - lsum;
    const int total = sscan[255];

    float* ob  = out + n * POST_N * 4;
    float* osc = out + NIMG * POST_N * 4 + n * POST_N;
    float* ovd = out + NIMG * POST_N * 5 + n * POST_N;

    for (int i = tid; i < POST_N * 4; i += 256) ob[i] = 0.0f;
    for (int i = tid; i < POST_N; i += 256) osc[i] = 0.0f;
    const int lim = min(total, POST_N);
    for (int i = tid; i < POST_N; i += 256) ovd[i] = (i < lim) ? 1.0f : 0.0f;
    __syncthreads();

    int run = excl;
    for (int q = 0; q < 8; ++q) {
        const int i = base8 + q;
        if (i < PRE_N && c[q]) {
            if (run < POST_N) {
                float4 b = ((const float4*)wsBoxes)[n * PRE_N + i];
                ob[run * 4 + 0] = b.x;
                ob[run * 4 + 1] = b.y;
                ob[run * 4 + 2] = b.z;
                ob[run * 4 + 3] = b.w;
                osc[run] = wsScores[n * PRE_N + i];
            }
            run++;
        }
    }
}

extern "C" void kernel_launch(void* const* d_in, const int* in_sizes, int n_in,
                              void* d_out, int out_size, void* d_ws, size_t ws_size,
                              hipStream_t stream) {
    const float* obj  = (const float*)d_in[0];
    const float* breg = (const float*)d_in[1];
    // d_in[2] anchors unused (computed inline, exact in f32)
    float* ws        = (float*)d_ws;
    float* wsBoxes   = ws;                      // 64000 floats
    float* wsScores  = ws + 64000;              // 16000 floats
    int*   wsValid   = (int*)(ws + 80000);      // 16000 ints
    uint64_t* wsMask = (uint64_t*)(ws + 96000); // 8*2000*32 u64 = 4 MB
    // candBuf/candCnt alias the mask region (dead until nms_mask runs)
    uint64_t*     candBuf = wsMask;                           // 8*4096 u64
    unsigned int* candCnt = (unsigned int*)(wsMask + NIMG * CAND_MAX);

    hist_compact<<<NIMG, 1024, 0, stream>>>(obj, candBuf, candCnt);
    rank_decode<<<NIMG * 32, 128, 0, stream>>>(breg, candBuf, candCnt,
                                               wsBoxes, wsScores, wsValid);
    nms_mask<<<NIMG * 32, 256, 0, stream>>>(wsBoxes, wsMask);
    nms_scan_select<<<NIMG, 256, 0, stream>>>(wsBoxes, wsScores, wsValid, wsMask,
                                              (float*)d_out);
}

// Round 8
// 207.632 us; speedup vs baseline: 1.8929x; 1.2318x over previous
//
#include <hip/hip_runtime.h>
#include <math.h>
#include <stdint.h>

#define NIMG   8
#define NA     30000      // H*W*A = 100*100*3
#define PRE_N  2000
#define POST_N 1000
#define NMS_TH 0.7f
#define DCLIP  4.135166556742356f   // log(1000/16)
#define IMGF   1600.0f
#define IMGM1  1599.0f
#define CAND_MAX 4096

// ws layout (floats): boxes [8][2000][4] @0, scores [8][2000] @64000,
//   valid(int) [8][2000] @80000, mask(u64) [8][2000][32] @96000.
// candBuf (u64 [8][4096]) + candCnt alias the START of the mask region
// (dead until nms_mask runs; same stream => safe).

// ---------------------------------------------------------------------------
// Kernel A (unchanged, verified): histogram + boundary bin + compact.
// ---------------------------------------------------------------------------
__global__ __launch_bounds__(1024) void hist_compact(
    const float* __restrict__ obj,
    uint64_t* __restrict__ candBuf, unsigned int* __restrict__ candCnt)
{
    const int n    = blockIdx.x;
    const int tid  = threadIdx.x;
    const int lane = tid & 63;
    const int wid  = tid >> 6;

    __shared__ unsigned int hist[4096];
    __shared__ unsigned int wsum[16];
    __shared__ unsigned int scal[4];

    for (int b = tid; b < 4096; b += 1024) hist[b] = 0u;
    if (tid < 4) scal[tid] = 0u;
    __syncthreads();

    const float* objn = obj + n * NA;

    for (int j = tid; j < NA; j += 1024) {
        unsigned int u = __float_as_uint(objn[j]);
        unsigned int k = (u & 0x80000000u) ? ~u : (u | 0x80000000u);
        atomicAdd(&hist[k >> 20], 1u);
    }
    __syncthreads();

    unsigned int c0 = hist[tid*4+0], c1 = hist[tid*4+1],
                 c2 = hist[tid*4+2], c3 = hist[tid*4+3];
    unsigned int p = c0 + c1 + c2 + c3;
    unsigned int s = p;
    #pragma unroll
    for (int off = 1; off < 64; off <<= 1) {
        unsigned int v = __shfl_down(s, off);
        if (lane + off < 64) s += v;
    }
    if (lane == 0) wsum[wid] = s;
    __syncthreads();
    unsigned int wafter = 0;
    for (int w = wid + 1; w < 16; ++w) wafter += wsum[w];
    unsigned int after = (s - p) + wafter;
    {
        unsigned int S3 = after + c3;
        unsigned int S2 = S3 + c2;
        unsigned int S1 = S2 + c1;
        unsigned int S0 = S1 + c0;
        if (S3 >= PRE_N && after < PRE_N) { scal[2] = tid*4+3; }
        if (S2 >= PRE_N && S3    < PRE_N) { scal[2] = tid*4+2; }
        if (S1 >= PRE_N && S2    < PRE_N) { scal[2] = tid*4+1; }
        if (S0 >= PRE_N && S1    < PRE_N) { scal[2] = tid*4+0; }
    }
    __syncthreads();
    const unsigned int bstar = scal[2];

    for (int j = tid; j < NA; j += 1024) {
        unsigned int u = __float_as_uint(objn[j]);
        unsigned int k = (u & 0x80000000u) ? ~u : (u | 0x80000000u);
        if ((k >> 20) < bstar) continue;
        int a = j / 10000, t = j - a * 10000;
        uint64_t key = (((uint64_t)(~k)) << 32) | (unsigned int)(t * 3 + a);
        unsigned int pos = atomicAdd(&scal[0], 1u);
        if (pos < CAND_MAX) candBuf[n * CAND_MAX + pos] = key;
    }
    __syncthreads();
    if (tid == 0) candCnt[n] = min(scal[0], (unsigned int)CAND_MAX);
}

// ---------------------------------------------------------------------------
// Kernel B (unchanged, verified): parallel rank-by-counting + decode.
// ---------------------------------------------------------------------------
__global__ __launch_bounds__(128) void rank_decode(
    const float* __restrict__ breg,
    const uint64_t* __restrict__ candBuf, const unsigned int* __restrict__ candCnt,
    float* __restrict__ wsBoxes, float* __restrict__ wsScores,
    int* __restrict__ wsValid)
{
    const int n    = blockIdx.x >> 5;
    const int tile = blockIdx.x & 31;
    const int tid  = threadIdx.x;

    __shared__ uint64_t keys[CAND_MAX];

    const int C = (int)candCnt[n];
    if (tile * 128 >= C) return;

    for (int i = tid; i < C; i += 128) keys[i] = candBuf[n * CAND_MAX + i];
    __syncthreads();

    const int my = tile * 128 + tid;
    if (my >= C) return;
    const uint64_t km = keys[my];
    unsigned int rank = 0;
    for (int j = 0; j < C; ++j) rank += (keys[j] < km);
    if (rank >= PRE_N) return;

    unsigned int idx = (unsigned int)km;
    unsigned int k   = ~((unsigned int)(km >> 32));
    unsigned int u   = (k & 0x80000000u) ? (k & 0x7fffffffu) : ~k;
    float logit = __uint_as_float(u);
    float score = 1.0f / (1.0f + expf(-logit));

    int a = idx % 3, t = idx / 3, w = t % 100, h = t / 100;
    const float* bp = breg + n*120000 + (a*4)*10000 + t;
    float dx = bp[0], dy = bp[10000], dw = bp[20000], dh = bp[30000];

    float half = (a == 0) ? 32.0f : ((a == 1) ? 64.0f : 128.0f);
    float cx = w * 16.0f + 8.0f, cy = h * 16.0f + 8.0f;
    float x1 = cx - half, y1 = cy - half, x2 = cx + half, y2 = cy + half;
    float wd = x2 - x1 + 1.0f, hg = y2 - y1 + 1.0f;
    float cxr = x1 + 0.5f * wd, cyr = y1 + 0.5f * hg;
    dw = fminf(dw, DCLIP); dh = fminf(dh, DCLIP);
    float pcx = dx * wd + cxr, pcy = dy * hg + cyr;
    float pw = expf(dw) * wd, ph = expf(dh) * hg;
    float px1 = pcx - 0.5f * pw, py1 = pcy - 0.5f * ph;
    float px2 = pcx + 0.5f * pw - 1.0f, py2 = pcy + 0.5f * ph - 1.0f;
    px1 = fminf(fmaxf(px1, 0.0f), IMGM1);
    px2 = fminf(fmaxf(px2, 0.0f), IMGM1);
    py1 = fminf(fmaxf(py1, 0.0f), IMGM1);
    py2 = fminf(fmaxf(py2, 0.0f), IMGM1);
    float wss = px2 - px1 + 1.0f, hss = py2 - py1 + 1.0f;
    float xc = px1 + wss * 0.5f, yc = py1 + hss * 0.5f;
    int valid = (wss >= 0.0f) && (hss >= 0.0f) && (xc < IMGF) && (yc < IMGF);

    ((float4*)wsBoxes)[n * PRE_N + (int)rank] = make_float4(px1, py1, px2, py2);
    wsScores[n * PRE_N + (int)rank] = score;
    wsValid [n * PRE_N + (int)rank] = valid;
}

// ---------------------------------------------------------------------------
// Kernel C (R8): one WAVE per (image, row-tile, col-tile). Row boxes in
// registers, broadcast via v_readlane (const index, fully unrolled); the
// 64 column IoUs of a row ARE a __ballot. Lane c latches row c's word;
// one scatter store per tile. Lower-triangle pairs store zeros. No LDS.
// ---------------------------------------------------------------------------
__global__ __launch_bounds__(64) void nms_mask(
    const float* __restrict__ wsBoxes, uint64_t* __restrict__ mask)
{
    const int blk  = blockIdx.x;
    const int n    = blk >> 10;
    const int i_t  = (blk >> 5) & 31;
    const int j_t  = blk & 31;
    const int lane = threadIdx.x;

    uint64_t* mrow = mask + ((size_t)n * PRE_N + (size_t)i_t * 64) * 32;
    const int cmax = (i_t == 31) ? 16 : 64;    // rows >= 2000 don't exist

    if (j_t < i_t) {                            // lower triangle: zeros
        if (lane < cmax) mrow[(size_t)lane * 32 + j_t] = 0ull;
        return;
    }

    const int r = i_t * 64 + lane;
    float4 rb = (r < PRE_N) ? ((const float4*)wsBoxes)[n * PRE_N + r]
                            : make_float4(0.f, 0.f, 0.f, 0.f);
    float ra = (rb.z - rb.x + 1.0f) * (rb.w - rb.y + 1.0f);

    const int j = j_t * 64 + lane;
    float4 cb = (j < PRE_N) ? ((const float4*)wsBoxes)[n * PRE_N + j]
                            : make_float4(3e30f, 3e30f, 3e30f, 3e30f);
    float ca = (cb.z - cb.x + 1.0f) * (cb.w - cb.y + 1.0f);

    const uint64_t jmask = (j_t == 31) ? 0xFFFFull : ~0ull;
    const bool diag = (j_t == i_t);
    uint64_t myword = 0ull;

    #pragma unroll
    for (int c = 0; c < 64; ++c) {
        float rx1 = __int_as_float(__builtin_amdgcn_readlane(__float_as_int(rb.x), c));
        float ry1 = __int_as_float(__builtin_amdgcn_readlane(__float_as_int(rb.y), c));
        float rx2 = __int_as_float(__builtin_amdgcn_readlane(__float_as_int(rb.z), c));
        float ry2 = __int_as_float(__builtin_amdgcn_readlane(__float_as_int(rb.w), c));
        float rar = __int_as_float(__builtin_amdgcn_readlane(__float_as_int(ra), c));
        float xx1 = fmaxf(rx1, cb.x), yy1 = fmaxf(ry1, cb.y);
        float xx2 = fminf(rx2, cb.z), yy2 = fminf(ry2, cb.w);
        float ww = fmaxf(xx2 - xx1 + 1.0f, 0.0f);
        float hh = fmaxf(yy2 - yy1 + 1.0f, 0.0f);
        float inter = ww * hh;
        float iou = inter / (rar + ca - inter);
        unsigned long long bits = __ballot(iou > NMS_TH) & jmask;
        if (diag) bits &= (c == 63) ? 0ull : ((~0ull) << (c + 1));
        if (lane == c) myword = bits;
    }
    if (lane < cmax) mrow[(size_t)lane * 32 + j_t] = myword;
}

// ---------------------------------------------------------------------------
// Kernel D (R8): serial greedy scan, inline asm. Same 64-slot VGPR ring,
// but the per-row critical chain is now PURE SALU: readlane of the row word
// is hoisted off-chain (independent of `win`); chain = bitcmp->cselect->
// s_and->s_or (~4 SALU/row). Early-exit at kept=1000 (output-identical).
// ---------------------------------------------------------------------------
#define SL(n,b) \
    "global_load_dword v" #n ", %[voff], %[sbase]\n\t" \
    "v_add_u32 %[voff], 0x100, %[voff]\n\t"

#define SS(n,b) \
    "s_waitcnt vmcnt(63)\n\t" \
    "v_readlane_b32 %[t], v" #n ", %[lw]\n\t" \
    "s_bitcmp1_b32 %[win], " #b "\n\t" \
    "s_cselect_b32 %[m], 0, -1\n\t" \
    "s_sub_i32 %[kept], %[kept], %[m]\n\t" \
    "s_and_b32 %[t], %[t], %[m]\n\t" \
    "s_or_b32 %[win], %[win], %[t]\n\t" \
    "v_and_b32 v" #n ", %[m], v" #n "\n\t" \
    "v_or_b32 %[rem], %[rem], v" #n "\n\t" \
    "global_load_dword v" #n ", %[voff], %[sbase]\n\t" \
    "v_add_u32 %[voff], 0x100, %[voff]\n\t"

#define SN(n,b,w) \
    "s_waitcnt vmcnt(" #w ")\n\t" \
    "v_readlane_b32 %[t], v" #n ", %[lw]\n\t" \
    "s_bitcmp1_b32 %[win], " #b "\n\t" \
    "s_cselect_b32 %[m], 0, -1\n\t" \
    "s_sub_i32 %[kept], %[kept], %[m]\n\t" \
    "s_and_b32 %[t], %[t], %[m]\n\t" \
    "s_or_b32 %[win], %[win], %[t]\n\t" \
    "v_and_b32 v" #n ", %[m], v" #n "\n\t" \
    "v_or_b32 %[rem], %[rem], v" #n "\n\t"

#define SWIN \
    "s_add_u32 %[lw], %[lw], 1\n\t" \
    "v_readlane_b32 %[t], %[rem], %[lw]\n\t" \
    "s_mov_b32 %[win], %[t]\n\t"

#define ROW_A(M) M(64,0) M(65,1) M(66,2) M(67,3) M(68,4) M(69,5) M(70,6) M(71,7) \
    M(72,8) M(73,9) M(74,10) M(75,11) M(76,12) M(77,13) M(78,14) M(79,15) \
    M(80,16) M(81,17) M(82,18) M(83,19) M(84,20) M(85,21) M(86,22) M(87,23) \
    M(88,24) M(89,25) M(90,26) M(91,27) M(92,28) M(93,29) M(94,30) M(95,31)
#define ROW_B(M) M(96,0) M(97,1) M(98,2) M(99,3) M(100,4) M(101,5) M(102,6) M(103,7) \
    M(104,8) M(105,9) M(106,10) M(107,11) M(108,12) M(109,13) M(110,14) M(111,15) \
    M(112,16) M(113,17) M(114,18) M(115,19) M(116,20) M(117,21) M(118,22) M(119,23) \
    M(120,24) M(121,25) M(122,26) M(123,27) M(124,28) M(125,29) M(126,30) M(127,31)

__global__ __launch_bounds__(256) void nms_scan_select(
    const float* __restrict__ wsBoxes, const float* __restrict__ wsScores,
    const int* __restrict__ wsValid, const uint64_t* __restrict__ mask,
    float* __restrict__ out)
{
    const int n   = blockIdx.x;
    const int tid = threadIdx.x;

    __shared__ __align__(8) unsigned char invb[256];
    __shared__ unsigned int keepw32[64];
    __shared__ int sscan[256];

    unsigned int byte = 0xFFu;
    if (tid < PRE_N / 8) {
        byte = 0u;
        for (int q = 0; q < 8; ++q)
            byte |= (wsValid[n * PRE_N + tid * 8 + q] ? 0u : 1u) << q;
    }
    invb[tid] = (unsigned char)byte;
    __syncthreads();

    if (tid < 64) {
        unsigned int rem = ((const unsigned int*)invb)[tid];
        unsigned long long sbase =
            (unsigned long long)(const void*)(mask + (size_t)n * PRE_N * 32);
        unsigned int voff = (unsigned int)(tid * 4);
        int win_, m_, t_, lw_, kept_, cnt_;

        asm volatile(
            "s_waitcnt vmcnt(0) lgkmcnt(0)\n\t"
            "s_mov_b32 %[kept], 0\n\t"
            "s_mov_b32 %[lw], 0\n\t"
            ROW_A(SL) ROW_B(SL)
            "v_readlane_b32 %[t], %[rem], %[lw]\n\t"
            "s_mov_b32 %[win], %[t]\n\t"
            "s_mov_b32 %[cnt], 30\n\t"
            "Lnms_%=:\n\t"
            ROW_A(SS)
            SWIN
            ROW_B(SS)
            SWIN
            "s_cmp_ge_i32 %[kept], 0x3e8\n\t"
            "s_cbranch_scc1 Lend_%=\n\t"
            "s_sub_u32 %[cnt], %[cnt], 1\n\t"
            "s_cmp_lg_u32 %[cnt], 0\n\t"
            "s_cbranch_scc1 Lnms_%=\n\t"
            SS(64,0) SS(65,1) SS(66,2) SS(67,3) SS(68,4) SS(69,5) SS(70,6) SS(71,7)
            SS(72,8) SS(73,9) SS(74,10) SS(75,11) SS(76,12) SS(77,13) SS(78,14) SS(79,15)
            SN(80,16,63) SN(81,17,62) SN(82,18,61) SN(83,19,60)
            SN(84,20,59) SN(85,21,58) SN(86,22,57) SN(87,23,56)
            SN(88,24,55) SN(89,25,54) SN(90,26,53) SN(91,27,52)
            SN(92,28,51) SN(93,29,50) SN(94,30,49) SN(95,31,48)
            SWIN
            SN(96,0,47) SN(97,1,46) SN(98,2,45) SN(99,3,44)
            SN(100,4,43) SN(101,5,42) SN(102,6,41) SN(103,7,40)
            SN(104,8,39) SN(105,9,38) SN(106,10,37) SN(107,11,36)
            SN(108,12,35) SN(109,13,34) SN(110,14,33) SN(111,15,32)
            SN(112,16,31) SN(113,17,30) SN(114,18,29) SN(115,19,28)
            SN(116,20,27) SN(117,21,26) SN(118,22,25) SN(119,23,24)
            SN(120,24,23) SN(121,25,22) SN(122,26,21) SN(123,27,20)
            SN(124,28,19) SN(125,29,18) SN(126,30,17) SN(127,31,16)
            SWIN
            SN(64,0,15) SN(65,1,14) SN(66,2,13) SN(67,3,12)
            SN(68,4,11) SN(69,5,10) SN(70,6,9) SN(71,7,8)
            SN(72,8,7) SN(73,9,6) SN(74,10,5) SN(75,11,4)
            SN(76,12,3) SN(77,13,2) SN(78,14,1) SN(79,15,0)
            "Lend_%=:\n\t"
            "s_waitcnt vmcnt(0)\n\t"
            : [rem]"+v"(rem), [voff]"+v"(voff),
              [win]"=&s"(win_), [m]"=&s"(m_), [t]"=&s"(t_),
              [lw]"=&s"(lw_), [kept]"=&s"(kept_), [cnt]"=&s"(cnt_)
            : [sbase]"s"(sbase)
            : "scc", "vcc", "memory",
              "v64","v65","v66","v67","v68","v69","v70","v71",
              "v72","v73","v74","v75","v76","v77","v78","v79",
              "v80","v81","v82","v83","v84","v85","v86","v87",
              "v88","v89","v90","v91","v92","v93","v94","v95",
              "v96","v97","v98","v99","v100","v101","v102","v103",
              "v104","v105","v106","v107","v108","v109","v110","v111",
              "v112","v113","v114","v115","v116","v117","v118","v119",
              "v120","v121","v122","v123","v124","v125","v126","v127");

        keepw32[tid] = ~rem;
    }
    __syncthreads();

    int c[8]; const int base8 = tid * 8;
    int lsum = 0;
    for (int q = 0; q < 8; ++q) {
        const int i = base8 + q;
        c[q] = (i < PRE_N) ? (int)((keepw32[i >> 5] >> (i & 31)) & 1u) : 0;
        lsum += c[q];
    }
    sscan[tid] = lsum;
    __syncthreads();
    for (int off = 1; off < 256; off <<= 1) {
        int v = (tid >= off) ? sscan[tid - off] : 0;
        __syncthreads();
        sscan[tid] += v;
        __syncthreads();
    }
    const int excl  = sscan[tid] - lsum;
    const int total = sscan[255];

    float* ob  = out + n * POST_N * 4;
    float* osc = out + NIMG * POST_N * 4 + n * POST_N;
    float* ovd = out + NIMG * POST_N * 5 + n * POST_N;

    for (int i = tid; i < POST_N * 4; i += 256) ob[i] = 0.0f;
    for (int i = tid; i < POST_N; i += 256) osc[i] = 0.0f;
    const int lim = min(total, POST_N);
    for (int i = tid; i < POST_N; i += 256) ovd[i] = (i < lim) ? 1.0f : 0.0f;
    __syncthreads();

    int run = excl;
    for (int q = 0; q < 8; ++q) {
        const int i = base8 + q;
        if (i < PRE_N && c[q]) {
            if (run < POST_N) {
                float4 b = ((const float4*)wsBoxes)[n * PRE_N + i];
                ob[run * 4 + 0] = b.x;
                ob[run * 4 + 1] = b.y;
                ob[run * 4 + 2] = b.z;
                ob[run * 4 + 3] = b.w;
                osc[run] = wsScores[n * PRE_N + i];
            }
            run++;
        }
    }
}

extern "C" void kernel_launch(void* const* d_in, const int* in_sizes, int n_in,
                              void* d_out, int out_size, void* d_ws, size_t ws_size,
                              hipStream_t stream) {
    const float* obj  = (const float*)d_in[0];
    const float* breg = (const float*)d_in[1];
    float* ws        = (float*)d_ws;
    float* wsBoxes   = ws;                      // 64000 floats
    float* wsScores  = ws + 64000;              // 16000 floats
    int*   wsValid   = (int*)(ws + 80000);      // 16000 ints
    uint64_t* wsMask = (uint64_t*)(ws + 96000); // 8*2000*32 u64 = 4 MB
    uint64_t*     candBuf = wsMask;
    unsigned int* candCnt = (unsigned int*)(wsMask + NIMG * CAND_MAX);

    hist_compact<<<NIMG, 1024, 0, stream>>>(obj, candBuf, candCnt);
    rank_decode<<<NIMG * 32, 128, 0, stream>>>(breg, candBuf, candCnt,
                                               wsBoxes, wsScores, wsValid);
    nms_mask<<<NIMG * 32 * 32, 64, 0, stream>>>(wsBoxes, wsMask);
    nms_scan_select<<<NIMG, 256, 0, stream>>>(wsBoxes, wsScores, wsValid, wsMask,
                                              (float*)d_out);
}

// Round 9
// 195.373 us; speedup vs baseline: 2.0117x; 1.0627x over previous
//
#include <hip/hip_runtime.h>
#include <math.h>
#include <stdint.h>

#define NIMG   8
#define NA     30000      // H*W*A = 100*100*3
#define PRE_N  2000
#define POST_N 1000
#define NMS_TH 0.7f
#define DCLIP  4.135166556742356f   // log(1000/16)
#define IMGF   1600.0f
#define IMGM1  1599.0f
#define CAND_MAX 4096

// ws layout (floats): boxes [8][2000][4] @0, scores [8][2000] @64000,
//   valid(int) [8][2000] @80000, mask(u64) [8][2000][32] @96000.
// candBuf (u64 [8][4096]) + candCnt alias the START of the mask region
// (dead until nms_mask runs; same stream => safe).

// ---------------------------------------------------------------------------
// Kernel A (unchanged, verified): histogram + boundary bin + compact.
// ---------------------------------------------------------------------------
__global__ __launch_bounds__(1024) void hist_compact(
    const float* __restrict__ obj,
    uint64_t* __restrict__ candBuf, unsigned int* __restrict__ candCnt)
{
    const int n    = blockIdx.x;
    const int tid  = threadIdx.x;
    const int lane = tid & 63;
    const int wid  = tid >> 6;

    __shared__ unsigned int hist[4096];
    __shared__ unsigned int wsum[16];
    __shared__ unsigned int scal[4];

    for (int b = tid; b < 4096; b += 1024) hist[b] = 0u;
    if (tid < 4) scal[tid] = 0u;
    __syncthreads();

    const float* objn = obj + n * NA;

    for (int j = tid; j < NA; j += 1024) {
        unsigned int u = __float_as_uint(objn[j]);
        unsigned int k = (u & 0x80000000u) ? ~u : (u | 0x80000000u);
        atomicAdd(&hist[k >> 20], 1u);
    }
    __syncthreads();

    unsigned int c0 = hist[tid*4+0], c1 = hist[tid*4+1],
                 c2 = hist[tid*4+2], c3 = hist[tid*4+3];
    unsigned int p = c0 + c1 + c2 + c3;
    unsigned int s = p;
    #pragma unroll
    for (int off = 1; off < 64; off <<= 1) {
        unsigned int v = __shfl_down(s, off);
        if (lane + off < 64) s += v;
    }
    if (lane == 0) wsum[wid] = s;
    __syncthreads();
    unsigned int wafter = 0;
    for (int w = wid + 1; w < 16; ++w) wafter += wsum[w];
    unsigned int after = (s - p) + wafter;
    {
        unsigned int S3 = after + c3;
        unsigned int S2 = S3 + c2;
        unsigned int S1 = S2 + c1;
        unsigned int S0 = S1 + c0;
        if (S3 >= PRE_N && after < PRE_N) { scal[2] = tid*4+3; }
        if (S2 >= PRE_N && S3    < PRE_N) { scal[2] = tid*4+2; }
        if (S1 >= PRE_N && S2    < PRE_N) { scal[2] = tid*4+1; }
        if (S0 >= PRE_N && S1    < PRE_N) { scal[2] = tid*4+0; }
    }
    __syncthreads();
    const unsigned int bstar = scal[2];

    for (int j = tid; j < NA; j += 1024) {
        unsigned int u = __float_as_uint(objn[j]);
        unsigned int k = (u & 0x80000000u) ? ~u : (u | 0x80000000u);
        if ((k >> 20) < bstar) continue;
        int a = j / 10000, t = j - a * 10000;
        uint64_t key = (((uint64_t)(~k)) << 32) | (unsigned int)(t * 3 + a);
        unsigned int pos = atomicAdd(&scal[0], 1u);
        if (pos < CAND_MAX) candBuf[n * CAND_MAX + pos] = key;
    }
    __syncthreads();
    if (tid == 0) candCnt[n] = min(scal[0], (unsigned int)CAND_MAX);
}

// ---------------------------------------------------------------------------
// Kernel B (R9): LDS-free rank-by-counting. One wave per 64 candidates.
// Lane owns km; per 64-key chunk lanes load coalesced u64s, then a fully
// unrolled v_readlane(const c) broadcast + u64 compare does 64 compares/step
// wave-wide. No LDS, no barriers, pure VALU throughput.
// ---------------------------------------------------------------------------
__global__ __launch_bounds__(64) void rank_decode(
    const float* __restrict__ breg,
    const uint64_t* __restrict__ candBuf, const unsigned int* __restrict__ candCnt,
    float* __restrict__ wsBoxes, float* __restrict__ wsScores,
    int* __restrict__ wsValid)
{
    const int n    = blockIdx.x >> 6;   // 64 tiles per image
    const int tile = blockIdx.x & 63;
    const int lane = threadIdx.x;

    const int C = (int)candCnt[n];
    if (tile * 64 >= C) return;          // uniform wave exit

    const uint64_t* cb = candBuf + n * CAND_MAX;
    const int my = tile * 64 + lane;
    const uint64_t km = (my < C) ? cb[my] : ~0ull;   // all lanes stay active

    unsigned int rank = 0;
    const int nch = (C + 63) >> 6;
    for (int ch = 0; ch < nch; ++ch) {
        const int j = ch * 64 + lane;
        uint64_t ck = (j < C) ? cb[j] : ~0ull;       // ~0 never < any real key
        unsigned int clo = (unsigned int)ck, chi = (unsigned int)(ck >> 32);
        #pragma unroll
        for (int c = 0; c < 64; ++c) {
            unsigned int lo = (unsigned int)__builtin_amdgcn_readlane((int)clo, c);
            unsigned int hi = (unsigned int)__builtin_amdgcn_readlane((int)chi, c);
            uint64_t kc = ((uint64_t)hi << 32) | lo;
            rank += (kc < km) ? 1u : 0u;
        }
    }
    if (my >= C || rank >= PRE_N) return;

    // decode + clip + valid (bit-exact math, verified R1-R8)
    unsigned int idx = (unsigned int)km;
    unsigned int k   = ~((unsigned int)(km >> 32));
    unsigned int u   = (k & 0x80000000u) ? (k & 0x7fffffffu) : ~k;
    float logit = __uint_as_float(u);
    float score = 1.0f / (1.0f + expf(-logit));

    int a = idx % 3, t = idx / 3, w = t % 100, h = t / 100;
    const float* bp = breg + n*120000 + (a*4)*10000 + t;
    float dx = bp[0], dy = bp[10000], dw = bp[20000], dh = bp[30000];

    float half = (a == 0) ? 32.0f : ((a == 1) ? 64.0f : 128.0f);
    float cx = w * 16.0f + 8.0f, cy = h * 16.0f + 8.0f;
    float x1 = cx - half, y1 = cy - half, x2 = cx + half, y2 = cy + half;
    float wd = x2 - x1 + 1.0f, hg = y2 - y1 + 1.0f;
    float cxr = x1 + 0.5f * wd, cyr = y1 + 0.5f * hg;
    dw = fminf(dw, DCLIP); dh = fminf(dh, DCLIP);
    float pcx = dx * wd + cxr, pcy = dy * hg + cyr;
    float pw = expf(dw) * wd, ph = expf(dh) * hg;
    float px1 = pcx - 0.5f * pw, py1 = pcy - 0.5f * ph;
    float px2 = pcx + 0.5f * pw - 1.0f, py2 = pcy + 0.5f * ph - 1.0f;
    px1 = fminf(fmaxf(px1, 0.0f), IMGM1);
    px2 = fminf(fmaxf(px2, 0.0f), IMGM1);
    py1 = fminf(fmaxf(py1, 0.0f), IMGM1);
    py2 = fminf(fmaxf(py2, 0.0f), IMGM1);
    float wss = px2 - px1 + 1.0f, hss = py2 - py1 + 1.0f;
    float xc = px1 + wss * 0.5f, yc = py1 + hss * 0.5f;
    int valid = (wss >= 0.0f) && (hss >= 0.0f) && (xc < IMGF) && (yc < IMGF);

    ((float4*)wsBoxes)[n * PRE_N + (int)rank] = make_float4(px1, py1, px2, py2);
    wsScores[n * PRE_N + (int)rank] = score;
    wsValid [n * PRE_N + (int)rank] = valid;
}

// ---------------------------------------------------------------------------
// Kernel C (unchanged, verified R8): one WAVE per (image, row-tile, col-tile);
// ballot IS the mask word; readlane row broadcast; no LDS.
// ---------------------------------------------------------------------------
__global__ __launch_bounds__(64) void nms_mask(
    const float* __restrict__ wsBoxes, uint64_t* __restrict__ mask)
{
    const int blk  = blockIdx.x;
    const int n    = blk >> 10;
    const int i_t  = (blk >> 5) & 31;
    const int j_t  = blk & 31;
    const int lane = threadIdx.x;

    uint64_t* mrow = mask + ((size_t)n * PRE_N + (size_t)i_t * 64) * 32;
    const int cmax = (i_t == 31) ? 16 : 64;    // rows >= 2000 don't exist

    if (j_t < i_t) {                            // lower triangle: zeros
        if (lane < cmax) mrow[(size_t)lane * 32 + j_t] = 0ull;
        return;
    }

    const int r = i_t * 64 + lane;
    float4 rb = (r < PRE_N) ? ((const float4*)wsBoxes)[n * PRE_N + r]
                            : make_float4(0.f, 0.f, 0.f, 0.f);
    float ra = (rb.z - rb.x + 1.0f) * (rb.w - rb.y + 1.0f);

    const int j = j_t * 64 + lane;
    float4 cb = (j < PRE_N) ? ((const float4*)wsBoxes)[n * PRE_N + j]
                            : make_float4(3e30f, 3e30f, 3e30f, 3e30f);
    float ca = (cb.z - cb.x + 1.0f) * (cb.w - cb.y + 1.0f);

    const uint64_t jmask = (j_t == 31) ? 0xFFFFull : ~0ull;
    const bool diag = (j_t == i_t);
    uint64_t myword = 0ull;

    #pragma unroll
    for (int c = 0; c < 64; ++c) {
        float rx1 = __int_as_float(__builtin_amdgcn_readlane(__float_as_int(rb.x), c));
        float ry1 = __int_as_float(__builtin_amdgcn_readlane(__float_as_int(rb.y), c));
        float rx2 = __int_as_float(__builtin_amdgcn_readlane(__float_as_int(rb.z), c));
        float ry2 = __int_as_float(__builtin_amdgcn_readlane(__float_as_int(rb.w), c));
        float rar = __int_as_float(__builtin_amdgcn_readlane(__float_as_int(ra), c));
        float xx1 = fmaxf(rx1, cb.x), yy1 = fmaxf(ry1, cb.y);
        float xx2 = fminf(rx2, cb.z), yy2 = fminf(ry2, cb.w);
        float ww = fmaxf(xx2 - xx1 + 1.0f, 0.0f);
        float hh = fmaxf(yy2 - yy1 + 1.0f, 0.0f);
        float inter = ww * hh;
        float iou = inter / (rar + ca - inter);
        unsigned long long bits = __ballot(iou > NMS_TH) & jmask;
        if (diag) bits &= (c == 63) ? 0ull : ((~0ull) << (c + 1));
        if (lane == c) myword = bits;
    }
    if (lane < cmax) mrow[(size_t)lane * 32 + j_t] = myword;
}

// ---------------------------------------------------------------------------
// Kernel D (unchanged, verified R8): serial greedy scan, inline asm, 64-slot
// VGPR ring, pure-SALU chain, early-exit at kept=1000.
// ---------------------------------------------------------------------------
#define SL(n,b) \
    "global_load_dword v" #n ", %[voff], %[sbase]\n\t" \
    "v_add_u32 %[voff], 0x100, %[voff]\n\t"

#define SS(n,b) \
    "s_waitcnt vmcnt(63)\n\t" \
    "v_readlane_b32 %[t], v" #n ", %[lw]\n\t" \
    "s_bitcmp1_b32 %[win], " #b "\n\t" \
    "s_cselect_b32 %[m], 0, -1\n\t" \
    "s_sub_i32 %[kept], %[kept], %[m]\n\t" \
    "s_and_b32 %[t], %[t], %[m]\n\t" \
    "s_or_b32 %[win], %[win], %[t]\n\t" \
    "v_and_b32 v" #n ", %[m], v" #n "\n\t" \
    "v_or_b32 %[rem], %[rem], v" #n "\n\t" \
    "global_load_dword v" #n ", %[voff], %[sbase]\n\t" \
    "v_add_u32 %[voff], 0x100, %[voff]\n\t"

#define SN(n,b,w) \
    "s_waitcnt vmcnt(" #w ")\n\t" \
    "v_readlane_b32 %[t], v" #n ", %[lw]\n\t" \
    "s_bitcmp1_b32 %[win], " #b "\n\t" \
    "s_cselect_b32 %[m], 0, -1\n\t" \
    "s_sub_i32 %[kept], %[kept], %[m]\n\t" \
    "s_and_b32 %[t], %[t], %[m]\n\t" \
    "s_or_b32 %[win], %[win], %[t]\n\t" \
    "v_and_b32 v" #n ", %[m], v" #n "\n\t" \
    "v_or_b32 %[rem], %[rem], v" #n "\n\t"

#define SWIN \
    "s_add_u32 %[lw], %[lw], 1\n\t" \
    "v_readlane_b32 %[t], %[rem], %[lw]\n\t" \
    "s_mov_b32 %[win], %[t]\n\t"

#define ROW_A(M) M(64,0) M(65,1) M(66,2) M(67,3) M(68,4) M(69,5) M(70,6) M(71,7) \
    M(72,8) M(73,9) M(74,10) M(75,11) M(76,12) M(77,13) M(78,14) M(79,15) \
    M(80,16) M(81,17) M(82,18) M(83,19) M(84,20) M(85,21) M(86,22) M(87,23) \
    M(88,24) M(89,25) M(90,26) M(91,27) M(92,28) M(93,29) M(94,30) M(95,31)
#define ROW_B(M) M(96,0) M(97,1) M(98,2) M(99,3) M(100,4) M(101,5) M(102,6) M(103,7) \
    M(104,8) M(105,9) M(106,10) M(107,11) M(108,12) M(109,13) M(110,14) M(111,15) \
    M(112,16) M(113,17) M(114,18) M(115,19) M(116,20) M(117,21) M(118,22) M(119,23) \
    M(120,24) M(121,25) M(122,26) M(123,27) M(124,28) M(125,29) M(126,30) M(127,31)

__global__ __launch_bounds__(256) void nms_scan_select(
    const float* __restrict__ wsBoxes, const float* __restrict__ wsScores,
    const int* __restrict__ wsValid, const uint64_t* __restrict__ mask,
    float* __restrict__ out)
{
    const int n   = blockIdx.x;
    const int tid = threadIdx.x;

    __shared__ __align__(8) unsigned char invb[256];
    __shared__ unsigned int keepw32[64];
    __shared__ int sscan[256];

    unsigned int byte = 0xFFu;
    if (tid < PRE_N / 8) {
        byte = 0u;
        for (int q = 0; q < 8; ++q)
            byte |= (wsValid[n * PRE_N + tid * 8 + q] ? 0u : 1u) << q;
    }
    invb[tid] = (unsigned char)byte;
    __syncthreads();

    if (tid < 64) {
        unsigned int rem = ((const unsigned int*)invb)[tid];
        unsigned long long sbase =
            (unsigned long long)(const void*)(mask + (size_t)n * PRE_N * 32);
        unsigned int voff = (unsigned int)(tid * 4);
        int win_, m_, t_, lw_, kept_, cnt_;

        asm volatile(
            "s_waitcnt vmcnt(0) lgkmcnt(0)\n\t"
            "s_mov_b32 %[kept], 0\n\t"
            "s_mov_b32 %[lw], 0\n\t"
            ROW_A(SL) ROW_B(SL)
            "v_readlane_b32 %[t], %[rem], %[lw]\n\t"
            "s_mov_b32 %[win], %[t]\n\t"
            "s_mov_b32 %[cnt], 30\n\t"
            "Lnms_%=:\n\t"
            ROW_A(SS)
            SWIN
            ROW_B(SS)
            SWIN
            "s_cmp_ge_i32 %[kept], 0x3e8\n\t"
            "s_cbranch_scc1 Lend_%=\n\t"
            "s_sub_u32 %[cnt], %[cnt], 1\n\t"
            "s_cmp_lg_u32 %[cnt], 0\n\t"
            "s_cbranch_scc1 Lnms_%=\n\t"
            SS(64,0) SS(65,1) SS(66,2) SS(67,3) SS(68,4) SS(69,5) SS(70,6) SS(71,7)
            SS(72,8) SS(73,9) SS(74,10) SS(75,11) SS(76,12) SS(77,13) SS(78,14) SS(79,15)
            SN(80,16,63) SN(81,17,62) SN(82,18,61) SN(83,19,60)
            SN(84,20,59) SN(85,21,58) SN(86,22,57) SN(87,23,56)
            SN(88,24,55) SN(89,25,54) SN(90,26,53) SN(91,27,52)
            SN(92,28,51) SN(93,29,50) SN(94,30,49) SN(95,31,48)
            SWIN
            SN(96,0,47) SN(97,1,46) SN(98,2,45) SN(99,3,44)
            SN(100,4,43) SN(101,5,42) SN(102,6,41) SN(103,7,40)
            SN(104,8,39) SN(105,9,38) SN(106,10,37) SN(107,11,36)
            SN(108,12,35) SN(109,13,34) SN(110,14,33) SN(111,15,32)
            SN(112,16,31) SN(113,17,30) SN(114,18,29) SN(115,19,28)
            SN(116,20,27) SN(117,21,26) SN(118,22,25) SN(119,23,24)
            SN(120,24,23) SN(121,25,22) SN(122,26,21) SN(123,27,20)
            SN(124,28,19) SN(125,29,18) SN(126,30,17) SN(127,31,16)
            SWIN
            SN(64,0,15) SN(65,1,14) SN(66,2,13) SN(67,3,12)
            SN(68,4,11) SN(69,5,10) SN(70,6,9) SN(71,7,8)
            SN(72,8,7) SN(73,9,6) SN(74,10,5) SN(75,11,4)
            SN(76,12,3) SN(77,13,2) SN(78,14,1) SN(79,15,0)
            "Lend_%=:\n\t"
            "s_waitcnt vmcnt(0)\n\t"
            : [rem]"+v"(rem), [voff]"+v"(voff),
              [win]"=&s"(win_), [m]"=&s"(m_), [t]"=&s"(t_),
              [lw]"=&s"(lw_), [kept]"=&s"(kept_), [cnt]"=&s"(cnt_)
            : [sbase]"s"(sbase)
            : "scc", "vcc", "memory",
              "v64","v65","v66","v67","v68","v69","v70","v71",
              "v72","v73","v74","v75","v76","v77","v78","v79",
              "v80","v81","v82","v83","v84","v85","v86","v87",
              "v88","v89","v90","v91","v92","v93","v94","v95",
              "v96","v97","v98","v99","v100","v101","v102","v103",
              "v104","v105","v106","v107","v108","v109","v110","v111",
              "v112","v113","v114","v115","v116","v117","v118","v119",
              "v120","v121","v122","v123","v124","v125","v126","v127");

        keepw32[tid] = ~rem;
    }
    __syncthreads();

    int c[8]; const int base8 = tid * 8;
    int lsum = 0;
    for (int q = 0; q < 8; ++q) {
        const int i = base8 + q;
        c[q] = (i < PRE_N) ? (int)((keepw32[i >> 5] >> (i & 31)) & 1u) : 0;
        lsum += c[q];
    }
    sscan[tid] = lsum;
    __syncthreads();
    for (int off = 1; off < 256; off <<= 1) {
        int v = (tid >= off) ? sscan[tid - off] : 0;
        __syncthreads();
        sscan[tid] += v;
        __syncthreads();
    }
    const int excl  = sscan[tid] - lsum;
    const int total = sscan[255];

    float* ob  = out + n * POST_N * 4;
    float* osc = out + NIMG * POST_N * 4 + n * POST_N;
    float* ovd = out + NIMG * POST_N * 5 + n * POST_N;

    for (int i = tid; i < POST_N * 4; i += 256) ob[i] = 0.0f;
    for (int i = tid; i < POST_N; i += 256) osc[i] = 0.0f;
    const int lim = min(total, POST_N);
    for (int i = tid; i < POST_N; i += 256) ovd[i] = (i < lim) ? 1.0f : 0.0f;
    __syncthreads();

    int run = excl;
    for (int q = 0; q < 8; ++q) {
        const int i = base8 + q;
        if (i < PRE_N && c[q]) {
            if (run < POST_N) {
                float4 b = ((const float4*)wsBoxes)[n * PRE_N + i];
                ob[run * 4 + 0] = b.x;
                ob[run * 4 + 1] = b.y;
                ob[run * 4 + 2] = b.z;
                ob[run * 4 + 3] = b.w;
                osc[run] = wsScores[n * PRE_N + i];
            }
            run++;
        }
    }
}

extern "C" void kernel_launch(void* const* d_in, const int* in_sizes, int n_in,
                              void* d_out, int out_size, void* d_ws, size_t ws_size,
                              hipStream_t stream) {
    const float* obj  = (const float*)d_in[0];
    const float* breg = (const float*)d_in[1];
    float* ws        = (float*)d_ws;
    float* wsBoxes   = ws;                      // 64000 floats
    float* wsScores  = ws + 64000;              // 16000 floats
    int*   wsValid   = (int*)(ws + 80000);      // 16000 ints
    uint64_t* wsMask = (uint64_t*)(ws + 96000); // 8*2000*32 u64 = 4 MB
    uint64_t*     candBuf = wsMask;
    unsigned int* candCnt = (unsigned int*)(wsMask + NIMG * CAND_MAX);

    hist_compact<<<NIMG, 1024, 0, stream>>>(obj, candBuf, candCnt);
    rank_decode<<<NIMG * 64, 64, 0, stream>>>(breg, candBuf, candCnt,
                                              wsBoxes, wsScores, wsValid);
    nms_mask<<<NIMG * 32 * 32, 64, 0, stream>>>(wsBoxes, wsMask);
    nms_scan_select<<<NIMG, 256, 0, stream>>>(wsBoxes, wsScores, wsValid, wsMask,
                                              (float*)d_out);
}

// Round 10
// 193.676 us; speedup vs baseline: 2.0293x; 1.0088x over previous
//
#include <hip/hip_runtime.h>
#include <math.h>
#include <stdint.h>

#define NIMG   8
#define NA     30000      // H*W*A = 100*100*3
#define PRE_N  2000
#define POST_N 1000
#define NMS_TH 0.7f
#define DCLIP  4.135166556742356f   // log(1000/16)
#define IMGF   1600.0f
#define IMGM1  1599.0f
#define CAND_MAX 4096

// ws layout (floats): boxes [8][2000][4] @0, scores [8][2000] @64000,
//   valid(int) [8][2000] @80000, mask(u64) [8][2000][32] @96000.
// candBuf (u64 [8][4096]) + candCnt alias the START of the mask region
// (dead until nms_mask runs; same stream => safe).

// ---------------------------------------------------------------------------
// Kernel A (unchanged, verified): histogram + boundary bin + compact.
// ---------------------------------------------------------------------------
__global__ __launch_bounds__(1024) void hist_compact(
    const float* __restrict__ obj,
    uint64_t* __restrict__ candBuf, unsigned int* __restrict__ candCnt)
{
    const int n    = blockIdx.x;
    const int tid  = threadIdx.x;
    const int lane = tid & 63;
    const int wid  = tid >> 6;

    __shared__ unsigned int hist[4096];
    __shared__ unsigned int wsum[16];
    __shared__ unsigned int scal[4];

    for (int b = tid; b < 4096; b += 1024) hist[b] = 0u;
    if (tid < 4) scal[tid] = 0u;
    __syncthreads();

    const float* objn = obj + n * NA;

    for (int j = tid; j < NA; j += 1024) {
        unsigned int u = __float_as_uint(objn[j]);
        unsigned int k = (u & 0x80000000u) ? ~u : (u | 0x80000000u);
        atomicAdd(&hist[k >> 20], 1u);
    }
    __syncthreads();

    unsigned int c0 = hist[tid*4+0], c1 = hist[tid*4+1],
                 c2 = hist[tid*4+2], c3 = hist[tid*4+3];
    unsigned int p = c0 + c1 + c2 + c3;
    unsigned int s = p;
    #pragma unroll
    for (int off = 1; off < 64; off <<= 1) {
        unsigned int v = __shfl_down(s, off);
        if (lane + off < 64) s += v;
    }
    if (lane == 0) wsum[wid] = s;
    __syncthreads();
    unsigned int wafter = 0;
    for (int w = wid + 1; w < 16; ++w) wafter += wsum[w];
    unsigned int after = (s - p) + wafter;
    {
        unsigned int S3 = after + c3;
        unsigned int S2 = S3 + c2;
        unsigned int S1 = S2 + c1;
        unsigned int S0 = S1 + c0;
        if (S3 >= PRE_N && after < PRE_N) { scal[2] = tid*4+3; }
        if (S2 >= PRE_N && S3    < PRE_N) { scal[2] = tid*4+2; }
        if (S1 >= PRE_N && S2    < PRE_N) { scal[2] = tid*4+1; }
        if (S0 >= PRE_N && S1    < PRE_N) { scal[2] = tid*4+0; }
    }
    __syncthreads();
    const unsigned int bstar = scal[2];

    for (int j = tid; j < NA; j += 1024) {
        unsigned int u = __float_as_uint(objn[j]);
        unsigned int k = (u & 0x80000000u) ? ~u : (u | 0x80000000u);
        if ((k >> 20) < bstar) continue;
        int a = j / 10000, t = j - a * 10000;
        uint64_t key = (((uint64_t)(~k)) << 32) | (unsigned int)(t * 3 + a);
        unsigned int pos = atomicAdd(&scal[0], 1u);
        if (pos < CAND_MAX) candBuf[n * CAND_MAX + pos] = key;
    }
    __syncthreads();
    if (tid == 0) candCnt[n] = min(scal[0], (unsigned int)CAND_MAX);
}

// ---------------------------------------------------------------------------
// Kernel B (unchanged, verified R9): LDS-free wave-wide rank-by-counting.
// ---------------------------------------------------------------------------
__global__ __launch_bounds__(64) void rank_decode(
    const float* __restrict__ breg,
    const uint64_t* __restrict__ candBuf, const unsigned int* __restrict__ candCnt,
    float* __restrict__ wsBoxes, float* __restrict__ wsScores,
    int* __restrict__ wsValid)
{
    const int n    = blockIdx.x >> 6;
    const int tile = blockIdx.x & 63;
    const int lane = threadIdx.x;

    const int C = (int)candCnt[n];
    if (tile * 64 >= C) return;

    const uint64_t* cb = candBuf + n * CAND_MAX;
    const int my = tile * 64 + lane;
    const uint64_t km = (my < C) ? cb[my] : ~0ull;

    unsigned int rank = 0;
    const int nch = (C + 63) >> 6;
    for (int ch = 0; ch < nch; ++ch) {
        const int j = ch * 64 + lane;
        uint64_t ck = (j < C) ? cb[j] : ~0ull;
        unsigned int clo = (unsigned int)ck, chi = (unsigned int)(ck >> 32);
        #pragma unroll
        for (int c = 0; c < 64; ++c) {
            unsigned int lo = (unsigned int)__builtin_amdgcn_readlane((int)clo, c);
            unsigned int hi = (unsigned int)__builtin_amdgcn_readlane((int)chi, c);
            uint64_t kc = ((uint64_t)hi << 32) | lo;
            rank += (kc < km) ? 1u : 0u;
        }
    }
    if (my >= C || rank >= PRE_N) return;

    unsigned int idx = (unsigned int)km;
    unsigned int k   = ~((unsigned int)(km >> 32));
    unsigned int u   = (k & 0x80000000u) ? (k & 0x7fffffffu) : ~k;
    float logit = __uint_as_float(u);
    float score = 1.0f / (1.0f + expf(-logit));

    int a = idx % 3, t = idx / 3, w = t % 100, h = t / 100;
    const float* bp = breg + n*120000 + (a*4)*10000 + t;
    float dx = bp[0], dy = bp[10000], dw = bp[20000], dh = bp[30000];

    float half = (a == 0) ? 32.0f : ((a == 1) ? 64.0f : 128.0f);
    float cx = w * 16.0f + 8.0f, cy = h * 16.0f + 8.0f;
    float x1 = cx - half, y1 = cy - half, x2 = cx + half, y2 = cy + half;
    float wd = x2 - x1 + 1.0f, hg = y2 - y1 + 1.0f;
    float cxr = x1 + 0.5f * wd, cyr = y1 + 0.5f * hg;
    dw = fminf(dw, DCLIP); dh = fminf(dh, DCLIP);
    float pcx = dx * wd + cxr, pcy = dy * hg + cyr;
    float pw = expf(dw) * wd, ph = expf(dh) * hg;
    float px1 = pcx - 0.5f * pw, py1 = pcy - 0.5f * ph;
    float px2 = pcx + 0.5f * pw - 1.0f, py2 = pcy + 0.5f * ph - 1.0f;
    px1 = fminf(fmaxf(px1, 0.0f), IMGM1);
    px2 = fminf(fmaxf(px2, 0.0f), IMGM1);
    py1 = fminf(fmaxf(py1, 0.0f), IMGM1);
    py2 = fminf(fmaxf(py2, 0.0f), IMGM1);
    float wss = px2 - px1 + 1.0f, hss = py2 - py1 + 1.0f;
    float xc = px1 + wss * 0.5f, yc = py1 + hss * 0.5f;
    int valid = (wss >= 0.0f) && (hss >= 0.0f) && (xc < IMGF) && (yc < IMGF);

    ((float4*)wsBoxes)[n * PRE_N + (int)rank] = make_float4(px1, py1, px2, py2);
    wsScores[n * PRE_N + (int)rank] = score;
    wsValid [n * PRE_N + (int)rank] = valid;
}

// ---------------------------------------------------------------------------
// Kernel C (R10): one BLOCK (8 waves) per (image, row-tile). R8's register/
// ballot compute per (wave, j_t); results staged in a padded LDS tile
// [64][33] u64 (2-way bank alias = free), then ONE contiguous coalesced
// 16 KB store per block. Fixes R9's 4x write amplification (17 MB -> 4.3 MB).
// ---------------------------------------------------------------------------
__global__ __launch_bounds__(512) void nms_mask(
    const float* __restrict__ wsBoxes, uint64_t* __restrict__ mask)
{
    const int blk  = blockIdx.x;
    const int n    = blk >> 5;
    const int i_t  = blk & 31;
    const int tid  = threadIdx.x;
    const int lane = tid & 63;
    const int wv   = tid >> 6;   // 0..7

    __shared__ uint64_t tile[64 * 33];   // padded pitch 33

    for (int idx = tid; idx < 64 * 33; idx += 512) tile[idx] = 0ull;
    __syncthreads();

    const int r = i_t * 64 + lane;
    float4 rb = (r < PRE_N) ? ((const float4*)wsBoxes)[n * PRE_N + r]
                            : make_float4(0.f, 0.f, 0.f, 0.f);
    float ra = (rb.z - rb.x + 1.0f) * (rb.w - rb.y + 1.0f);

    for (int j_t = i_t + wv; j_t < 32; j_t += 8) {
        const int j = j_t * 64 + lane;
        float4 cb = (j < PRE_N) ? ((const float4*)wsBoxes)[n * PRE_N + j]
                                : make_float4(3e30f, 3e30f, 3e30f, 3e30f);
        float ca = (cb.z - cb.x + 1.0f) * (cb.w - cb.y + 1.0f);
        const uint64_t jmask = (j_t == 31) ? 0xFFFFull : ~0ull;
        const bool diag = (j_t == i_t);
        uint64_t myword = 0ull;

        #pragma unroll
        for (int c = 0; c < 64; ++c) {
            float rx1 = __int_as_float(__builtin_amdgcn_readlane(__float_as_int(rb.x), c));
            float ry1 = __int_as_float(__builtin_amdgcn_readlane(__float_as_int(rb.y), c));
            float rx2 = __int_as_float(__builtin_amdgcn_readlane(__float_as_int(rb.z), c));
            float ry2 = __int_as_float(__builtin_amdgcn_readlane(__float_as_int(rb.w), c));
            float rar = __int_as_float(__builtin_amdgcn_readlane(__float_as_int(ra), c));
            float xx1 = fmaxf(rx1, cb.x), yy1 = fmaxf(ry1, cb.y);
            float xx2 = fminf(rx2, cb.z), yy2 = fminf(ry2, cb.w);
            float ww = fmaxf(xx2 - xx1 + 1.0f, 0.0f);
            float hh = fmaxf(yy2 - yy1 + 1.0f, 0.0f);
            float inter = ww * hh;
            float iou = inter / (rar + ca - inter);
            unsigned long long bits = __ballot(iou > NMS_TH) & jmask;
            if (diag) bits &= (c == 63) ? 0ull : ((~0ull) << (c + 1));
            if (lane == c) myword = bits;
        }
        tile[lane * 33 + j_t] = myword;   // 2-way bank alias only
    }
    __syncthreads();

    uint64_t* mrow = mask + ((size_t)n * PRE_N + (size_t)i_t * 64) * 32;
    const int cmax = (i_t == 31) ? 16 : 64;    // rows >= 2000 don't exist
    for (int idx = tid; idx < cmax * 32; idx += 512) {
        const int rr = idx >> 5, w = idx & 31;
        mrow[idx] = tile[rr * 33 + w];
    }
}

// ---------------------------------------------------------------------------
// Kernel D (unchanged, verified R8): serial greedy scan, inline asm, 64-slot
// VGPR ring, pure-SALU chain, early-exit at kept=1000.
// ---------------------------------------------------------------------------
#define SL(n,b) \
    "global_load_dword v" #n ", %[voff], %[sbase]\n\t" \
    "v_add_u32 %[voff], 0x100, %[voff]\n\t"

#define SS(n,b) \
    "s_waitcnt vmcnt(63)\n\t" \
    "v_readlane_b32 %[t], v" #n ", %[lw]\n\t" \
    "s_bitcmp1_b32 %[win], " #b "\n\t" \
    "s_cselect_b32 %[m], 0, -1\n\t" \
    "s_sub_i32 %[kept], %[kept], %[m]\n\t" \
    "s_and_b32 %[t], %[t], %[m]\n\t" \
    "s_or_b32 %[win], %[win], %[t]\n\t" \
    "v_and_b32 v" #n ", %[m], v" #n "\n\t" \
    "v_or_b32 %[rem], %[rem], v" #n "\n\t" \
    "global_load_dword v" #n ", %[voff], %[sbase]\n\t" \
    "v_add_u32 %[voff], 0x100, %[voff]\n\t"

#define SN(n,b,w) \
    "s_waitcnt vmcnt(" #w ")\n\t" \
    "v_readlane_b32 %[t], v" #n ", %[lw]\n\t" \
    "s_bitcmp1_b32 %[win], " #b "\n\t" \
    "s_cselect_b32 %[m], 0, -1\n\t" \
    "s_sub_i32 %[kept], %[kept], %[m]\n\t" \
    "s_and_b32 %[t], %[t], %[m]\n\t" \
    "s_or_b32 %[win], %[win], %[t]\n\t" \
    "v_and_b32 v" #n ", %[m], v" #n "\n\t" \
    "v_or_b32 %[rem], %[rem], v" #n "\n\t"

#define SWIN \
    "s_add_u32 %[lw], %[lw], 1\n\t" \
    "v_readlane_b32 %[t], %[rem], %[lw]\n\t" \
    "s_mov_b32 %[win], %[t]\n\t"

#define ROW_A(M) M(64,0) M(65,1) M(66,2) M(67,3) M(68,4) M(69,5) M(70,6) M(71,7) \
    M(72,8) M(73,9) M(74,10) M(75,11) M(76,12) M(77,13) M(78,14) M(79,15) \
    M(80,16) M(81,17) M(82,18) M(83,19) M(84,20) M(85,21) M(86,22) M(87,23) \
    M(88,24) M(89,25) M(90,26) M(91,27) M(92,28) M(93,29) M(94,30) M(95,31)
#define ROW_B(M) M(96,0) M(97,1) M(98,2) M(99,3) M(100,4) M(101,5) M(102,6) M(103,7) \
    M(104,8) M(105,9) M(106,10) M(107,11) M(108,12) M(109,13) M(110,14) M(111,15) \
    M(112,16) M(113,17) M(114,18) M(115,19) M(116,20) M(117,21) M(118,22) M(119,23) \
    M(120,24) M(121,25) M(122,26) M(123,27) M(124,28) M(125,29) M(126,30) M(127,31)

__global__ __launch_bounds__(256) void nms_scan_select(
    const float* __restrict__ wsBoxes, const float* __restrict__ wsScores,
    const int* __restrict__ wsValid, const uint64_t* __restrict__ mask,
    float* __restrict__ out)
{
    const int n   = blockIdx.x;
    const int tid = threadIdx.x;

    __shared__ __align__(8) unsigned char invb[256];
    __shared__ unsigned int keepw32[64];
    __shared__ int sscan[256];

    unsigned int byte = 0xFFu;
    if (tid < PRE_N / 8) {
        byte = 0u;
        for (int q = 0; q < 8; ++q)
            byte |= (wsValid[n * PRE_N + tid * 8 + q] ? 0u : 1u) << q;
    }
    invb[tid] = (unsigned char)byte;
    __syncthreads();

    if (tid < 64) {
        unsigned int rem = ((const unsigned int*)invb)[tid];
        unsigned long long sbase =
            (unsigned long long)(const void*)(mask + (size_t)n * PRE_N * 32);
        unsigned int voff = (unsigned int)(tid * 4);
        int win_, m_, t_, lw_, kept_, cnt_;

        asm volatile(
            "s_waitcnt vmcnt(0) lgkmcnt(0)\n\t"
            "s_mov_b32 %[kept], 0\n\t"
            "s_mov_b32 %[lw], 0\n\t"
            ROW_A(SL) ROW_B(SL)
            "v_readlane_b32 %[t], %[rem], %[lw]\n\t"
            "s_mov_b32 %[win], %[t]\n\t"
            "s_mov_b32 %[cnt], 30\n\t"
            "Lnms_%=:\n\t"
            ROW_A(SS)
            SWIN
            ROW_B(SS)
            SWIN
            "s_cmp_ge_i32 %[kept], 0x3e8\n\t"
            "s_cbranch_scc1 Lend_%=\n\t"
            "s_sub_u32 %[cnt], %[cnt], 1\n\t"
            "s_cmp_lg_u32 %[cnt], 0\n\t"
            "s_cbranch_scc1 Lnms_%=\n\t"
            SS(64,0) SS(65,1) SS(66,2) SS(67,3) SS(68,4) SS(69,5) SS(70,6) SS(71,7)
            SS(72,8) SS(73,9) SS(74,10) SS(75,11) SS(76,12) SS(77,13) SS(78,14) SS(79,15)
            SN(80,16,63) SN(81,17,62) SN(82,18,61) SN(83,19,60)
            SN(84,20,59) SN(85,21,58) SN(86,22,57) SN(87,23,56)
            SN(88,24,55) SN(89,25,54) SN(90,26,53) SN(91,27,52)
            SN(92,28,51) SN(93,29,50) SN(94,30,49) SN(95,31,48)
            SWIN
            SN(96,0,47) SN(97,1,46) SN(98,2,45) SN(99,3,44)
            SN(100,4,43) SN(101,5,42) SN(102,6,41) SN(103,7,40)
            SN(104,8,39) SN(105,9,38) SN(106,10,37) SN(107,11,36)
            SN(108,12,35) SN(109,13,34) SN(110,14,33) SN(111,15,32)
            SN(112,16,31) SN(113,17,30) SN(114,18,29) SN(115,19,28)
            SN(116,20,27) SN(117,21,26) SN(118,22,25) SN(119,23,24)
            SN(120,24,23) SN(121,25,22) SN(122,26,21) SN(123,27,20)
            SN(124,28,19) SN(125,29,18) SN(126,30,17) SN(127,31,16)
            SWIN
            SN(64,0,15) SN(65,1,14) SN(66,2,13) SN(67,3,12)
            SN(68,4,11) SN(69,5,10) SN(70,6,9) SN(71,7,8)
            SN(72,8,7) SN(73,9,6) SN(74,10,5) SN(75,11,4)
            SN(76,12,3) SN(77,13,2) SN(78,14,1) SN(79,15,0)
            "Lend_%=:\n\t"
            "s_waitcnt vmcnt(0)\n\t"
            : [rem]"+v"(rem), [voff]"+v"(voff),
              [win]"=&s"(win_), [m]"=&s"(m_), [t]"=&s"(t_),
              [lw]"=&s"(lw_), [kept]"=&s"(kept_), [cnt]"=&s"(cnt_)
            : [sbase]"s"(sbase)
            : "scc", "vcc", "memory",
              "v64","v65","v66","v67","v68","v69","v70","v71",
              "v72","v73","v74","v75","v76","v77","v78","v79",
              "v80","v81","v82","v83","v84","v85","v86","v87",
              "v88","v89","v90","v91","v92","v93","v94","v95",
              "v96","v97","v98","v99","v100","v101","v102","v103",
              "v104","v105","v106","v107","v108","v109","v110","v111",
              "v112","v113","v114","v115","v116","v117","v118","v119",
              "v120","v121","v122","v123","v124","v125","v126","v127");

        keepw32[tid] = ~rem;
    }
    __syncthreads();

    int c[8]; const int base8 = tid * 8;
    int lsum = 0;
    for (int q = 0; q < 8; ++q) {
        const int i = base8 + q;
        c[q] = (i < PRE_N) ? (int)((keepw32[i >> 5] >> (i & 31)) & 1u) : 0;
        lsum += c[q];
    }
    sscan[tid] = lsum;
    __syncthreads();
    for (int off = 1; off < 256; off <<= 1) {
        int v = (tid >= off) ? sscan[tid - off] : 0;
        __syncthreads();
        sscan[tid] += v;
        __syncthreads();
    }
    const int excl  = sscan[tid] - lsum;
    const int total = sscan[255];

    float* ob  = out + n * POST_N * 4;
    float* osc = out + NIMG * POST_N * 4 + n * POST_N;
    float* ovd = out + NIMG * POST_N * 5 + n * POST_N;

    for (int i = tid; i < POST_N * 4; i += 256) ob[i] = 0.0f;
    for (int i = tid; i < POST_N; i += 256) osc[i] = 0.0f;
    const int lim = min(total, POST_N);
    for (int i = tid; i < POST_N; i += 256) ovd[i] = (i < lim) ? 1.0f : 0.0f;
    __syncthreads();

    int run = excl;
    for (int q = 0; q < 8; ++q) {
        const int i = base8 + q;
        if (i < PRE_N && c[q]) {
            if (run < POST_N) {
                float4 b = ((const float4*)wsBoxes)[n * PRE_N + i];
                ob[run * 4 + 0] = b.x;
                ob[run * 4 + 1] = b.y;
                ob[run * 4 + 2] = b.z;
                ob[run * 4 + 3] = b.w;
                osc[run] = wsScores[n * PRE_N + i];
            }
            run++;
        }
    }
}

extern "C" void kernel_launch(void* const* d_in, const int* in_sizes, int n_in,
                              void* d_out, int out_size, void* d_ws, size_t ws_size,
                              hipStream_t stream) {
    const float* obj  = (const float*)d_in[0];
    const float* breg = (const float*)d_in[1];
    float* ws        = (float*)d_ws;
    float* wsBoxes   = ws;                      // 64000 floats
    float* wsScores  = ws + 64000;              // 16000 floats
    int*   wsValid   = (int*)(ws + 80000);      // 16000 ints
    uint64_t* wsMask = (uint64_t*)(ws + 96000); // 8*2000*32 u64 = 4 MB
    uint64_t*     candBuf = wsMask;
    unsigned int* candCnt = (unsigned int*)(wsMask + NIMG * CAND_MAX);

    hist_compact<<<NIMG, 1024, 0, stream>>>(obj, candBuf, candCnt);
    rank_decode<<<NIMG * 64, 64, 0, stream>>>(breg, candBuf, candCnt,
                                              wsBoxes, wsScores, wsValid);
    nms_mask<<<NIMG * 32, 512, 0, stream>>>(wsBoxes, wsMask);
    nms_scan_select<<<NIMG, 256, 0, stream>>>(wsBoxes, wsScores, wsValid, wsMask,
                                              (float*)d_out);
}

// Round 11
// 184.286 us; speedup vs baseline: 2.1327x; 1.0510x over previous
//
#include <hip/hip_runtime.h>
#include <math.h>
#include <stdint.h>

#define NIMG   8
#define NA     30000      // H*W*A = 100*100*3
#define PRE_N  2000
#define POST_N 1000
#define NMS_TH 0.7f
#define DCLIP  4.135166556742356f   // log(1000/16)
#define IMGF   1600.0f
#define IMGM1  1599.0f
#define CAND_MAX 4096

// ws layout (floats): boxes [8][2000][4] @0, scores [8][2000] @64000,
//   valid(int) [8][2000] @80000, mask(u64) [8][2000][32] @96000.
// candBuf (u64 [8][4096]) + candCnt alias the START of the mask region
// (dead until nms_mask runs; same stream => safe).

// ---------------------------------------------------------------------------
// Kernel A (unchanged, verified): histogram + boundary bin + compact.
// ---------------------------------------------------------------------------
__global__ __launch_bounds__(1024) void hist_compact(
    const float* __restrict__ obj,
    uint64_t* __restrict__ candBuf, unsigned int* __restrict__ candCnt)
{
    const int n    = blockIdx.x;
    const int tid  = threadIdx.x;
    const int lane = tid & 63;
    const int wid  = tid >> 6;

    __shared__ unsigned int hist[4096];
    __shared__ unsigned int wsum[16];
    __shared__ unsigned int scal[4];

    for (int b = tid; b < 4096; b += 1024) hist[b] = 0u;
    if (tid < 4) scal[tid] = 0u;
    __syncthreads();

    const float* objn = obj + n * NA;

    for (int j = tid; j < NA; j += 1024) {
        unsigned int u = __float_as_uint(objn[j]);
        unsigned int k = (u & 0x80000000u) ? ~u : (u | 0x80000000u);
        atomicAdd(&hist[k >> 20], 1u);
    }
    __syncthreads();

    unsigned int c0 = hist[tid*4+0], c1 = hist[tid*4+1],
                 c2 = hist[tid*4+2], c3 = hist[tid*4+3];
    unsigned int p = c0 + c1 + c2 + c3;
    unsigned int s = p;
    #pragma unroll
    for (int off = 1; off < 64; off <<= 1) {
        unsigned int v = __shfl_down(s, off);
        if (lane + off < 64) s += v;
    }
    if (lane == 0) wsum[wid] = s;
    __syncthreads();
    unsigned int wafter = 0;
    for (int w = wid + 1; w < 16; ++w) wafter += wsum[w];
    unsigned int after = (s - p) + wafter;
    {
        unsigned int S3 = after + c3;
        unsigned int S2 = S3 + c2;
        unsigned int S1 = S2 + c1;
        unsigned int S0 = S1 + c0;
        if (S3 >= PRE_N && after < PRE_N) { scal[2] = tid*4+3; }
        if (S2 >= PRE_N && S3    < PRE_N) { scal[2] = tid*4+2; }
        if (S1 >= PRE_N && S2    < PRE_N) { scal[2] = tid*4+1; }
        if (S0 >= PRE_N && S1    < PRE_N) { scal[2] = tid*4+0; }
    }
    __syncthreads();
    const unsigned int bstar = scal[2];

    for (int j = tid; j < NA; j += 1024) {
        unsigned int u = __float_as_uint(objn[j]);
        unsigned int k = (u & 0x80000000u) ? ~u : (u | 0x80000000u);
        if ((k >> 20) < bstar) continue;
        int a = j / 10000, t = j - a * 10000;
        uint64_t key = (((uint64_t)(~k)) << 32) | (unsigned int)(t * 3 + a);
        unsigned int pos = atomicAdd(&scal[0], 1u);
        if (pos < CAND_MAX) candBuf[n * CAND_MAX + pos] = key;
    }
    __syncthreads();
    if (tid == 0) candCnt[n] = min(scal[0], (unsigned int)CAND_MAX);
}

// ---------------------------------------------------------------------------
// Kernel B (unchanged, verified R9): LDS-free wave-wide rank-by-counting.
// ---------------------------------------------------------------------------
__global__ __launch_bounds__(64) void rank_decode(
    const float* __restrict__ breg,
    const uint64_t* __restrict__ candBuf, const unsigned int* __restrict__ candCnt,
    float* __restrict__ wsBoxes, float* __restrict__ wsScores,
    int* __restrict__ wsValid)
{
    const int n    = blockIdx.x >> 6;
    const int tile = blockIdx.x & 63;
    const int lane = threadIdx.x;

    const int C = (int)candCnt[n];
    if (tile * 64 >= C) return;

    const uint64_t* cb = candBuf + n * CAND_MAX;
    const int my = tile * 64 + lane;
    const uint64_t km = (my < C) ? cb[my] : ~0ull;

    unsigned int rank = 0;
    const int nch = (C + 63) >> 6;
    for (int ch = 0; ch < nch; ++ch) {
        const int j = ch * 64 + lane;
        uint64_t ck = (j < C) ? cb[j] : ~0ull;
        unsigned int clo = (unsigned int)ck, chi = (unsigned int)(ck >> 32);
        #pragma unroll
        for (int c = 0; c < 64; ++c) {
            unsigned int lo = (unsigned int)__builtin_amdgcn_readlane((int)clo, c);
            unsigned int hi = (unsigned int)__builtin_amdgcn_readlane((int)chi, c);
            uint64_t kc = ((uint64_t)hi << 32) | lo;
            rank += (kc < km) ? 1u : 0u;
        }
    }
    if (my >= C || rank >= PRE_N) return;

    unsigned int idx = (unsigned int)km;
    unsigned int k   = ~((unsigned int)(km >> 32));
    unsigned int u   = (k & 0x80000000u) ? (k & 0x7fffffffu) : ~k;
    float logit = __uint_as_float(u);
    float score = 1.0f / (1.0f + expf(-logit));

    int a = idx % 3, t = idx / 3, w = t % 100, h = t / 100;
    const float* bp = breg + n*120000 + (a*4)*10000 + t;
    float dx = bp[0], dy = bp[10000], dw = bp[20000], dh = bp[30000];

    float half = (a == 0) ? 32.0f : ((a == 1) ? 64.0f : 128.0f);
    float cx = w * 16.0f + 8.0f, cy = h * 16.0f + 8.0f;
    float x1 = cx - half, y1 = cy - half, x2 = cx + half, y2 = cy + half;
    float wd = x2 - x1 + 1.0f, hg = y2 - y1 + 1.0f;
    float cxr = x1 + 0.5f * wd, cyr = y1 + 0.5f * hg;
    dw = fminf(dw, DCLIP); dh = fminf(dh, DCLIP);
    float pcx = dx * wd + cxr, pcy = dy * hg + cyr;
    float pw = expf(dw) * wd, ph = expf(dh) * hg;
    float px1 = pcx - 0.5f * pw, py1 = pcy - 0.5f * ph;
    float px2 = pcx + 0.5f * pw - 1.0f, py2 = pcy + 0.5f * ph - 1.0f;
    px1 = fminf(fmaxf(px1, 0.0f), IMGM1);
    px2 = fminf(fmaxf(px2, 0.0f), IMGM1);
    py1 = fminf(fmaxf(py1, 0.0f), IMGM1);
    py2 = fminf(fmaxf(py2, 0.0f), IMGM1);
    float wss = px2 - px1 + 1.0f, hss = py2 - py1 + 1.0f;
    float xc = px1 + wss * 0.5f, yc = py1 + hss * 0.5f;
    int valid = (wss >= 0.0f) && (hss >= 0.0f) && (xc < IMGF) && (yc < IMGF);

    ((float4*)wsBoxes)[n * PRE_N + (int)rank] = make_float4(px1, py1, px2, py2);
    wsScores[n * PRE_N + (int)rank] = score;
    wsValid [n * PRE_N + (int)rank] = valid;
}

// ---------------------------------------------------------------------------
// Kernel C (R11): R10 structure, but the IoU predicate is DIVISION-FREE:
// inter/denom > TH  <=>  inter > TH*denom (denom>0 always). The f32 div
// (v_div_scale/v_div_fmas) serializes on VCC across the unrolled 64 steps —
// it was the 41us floor that survived both R9 and R10 restructures.
// ---------------------------------------------------------------------------
__global__ __launch_bounds__(512) void nms_mask(
    const float* __restrict__ wsBoxes, uint64_t* __restrict__ mask)
{
    const int blk  = blockIdx.x;
    const int n    = blk >> 5;
    const int i_t  = blk & 31;
    const int tid  = threadIdx.x;
    const int lane = tid & 63;
    const int wv   = tid >> 6;   // 0..7

    __shared__ uint64_t tile[64 * 33];   // padded pitch 33

    for (int idx = tid; idx < 64 * 33; idx += 512) tile[idx] = 0ull;
    __syncthreads();

    const int r = i_t * 64 + lane;
    float4 rb = (r < PRE_N) ? ((const float4*)wsBoxes)[n * PRE_N + r]
                            : make_float4(0.f, 0.f, 0.f, 0.f);
    float ra = (rb.z - rb.x + 1.0f) * (rb.w - rb.y + 1.0f);

    for (int j_t = i_t + wv; j_t < 32; j_t += 8) {
        const int j = j_t * 64 + lane;
        float4 cb = (j < PRE_N) ? ((const float4*)wsBoxes)[n * PRE_N + j]
                                : make_float4(3e30f, 3e30f, 3e30f, 3e30f);
        float ca = (cb.z - cb.x + 1.0f) * (cb.w - cb.y + 1.0f);
        const uint64_t jmask = (j_t == 31) ? 0xFFFFull : ~0ull;
        const bool diag = (j_t == i_t);
        uint64_t myword = 0ull;

        #pragma unroll
        for (int c = 0; c < 64; ++c) {
            float rx1 = __int_as_float(__builtin_amdgcn_readlane(__float_as_int(rb.x), c));
            float ry1 = __int_as_float(__builtin_amdgcn_readlane(__float_as_int(rb.y), c));
            float rx2 = __int_as_float(__builtin_amdgcn_readlane(__float_as_int(rb.z), c));
            float ry2 = __int_as_float(__builtin_amdgcn_readlane(__float_as_int(rb.w), c));
            float rar = __int_as_float(__builtin_amdgcn_readlane(__float_as_int(ra), c));
            float xx1 = fmaxf(rx1, cb.x), yy1 = fmaxf(ry1, cb.y);
            float xx2 = fminf(rx2, cb.z), yy2 = fminf(ry2, cb.w);
            float ww = fmaxf(xx2 - xx1 + 1.0f, 0.0f);
            float hh = fmaxf(yy2 - yy1 + 1.0f, 0.0f);
            float inter = ww * hh;
            float denom = rar + ca - inter;
            unsigned long long bits = __ballot(inter > NMS_TH * denom) & jmask;
            if (diag) bits &= (c == 63) ? 0ull : ((~0ull) << (c + 1));
            if (lane == c) myword = bits;
        }
        tile[lane * 33 + j_t] = myword;   // 2-way bank alias only
    }
    __syncthreads();

    uint64_t* mrow = mask + ((size_t)n * PRE_N + (size_t)i_t * 64) * 32;
    const int cmax = (i_t == 31) ? 16 : 64;    // rows >= 2000 don't exist
    for (int idx = tid; idx < cmax * 32; idx += 512) {
        const int rr = idx >> 5, w = idx & 31;
        mrow[idx] = tile[rr * 33 + w];
    }
}

// ---------------------------------------------------------------------------
// Kernel D (unchanged, verified R8): serial greedy scan, inline asm, 64-slot
// VGPR ring, pure-SALU chain, early-exit at kept=1000.
// ---------------------------------------------------------------------------
#define SL(n,b) \
    "global_load_dword v" #n ", %[voff], %[sbase]\n\t" \
    "v_add_u32 %[voff], 0x100, %[voff]\n\t"

#define SS(n,b) \
    "s_waitcnt vmcnt(63)\n\t" \
    "v_readlane_b32 %[t], v" #n ", %[lw]\n\t" \
    "s_bitcmp1_b32 %[win], " #b "\n\t" \
    "s_cselect_b32 %[m], 0, -1\n\t" \
    "s_sub_i32 %[kept], %[kept], %[m]\n\t" \
    "s_and_b32 %[t], %[t], %[m]\n\t" \
    "s_or_b32 %[win], %[win], %[t]\n\t" \
    "v_and_b32 v" #n ", %[m], v" #n "\n\t" \
    "v_or_b32 %[rem], %[rem], v" #n "\n\t" \
    "global_load_dword v" #n ", %[voff], %[sbase]\n\t" \
    "v_add_u32 %[voff], 0x100, %[voff]\n\t"

#define SN(n,b,w) \
    "s_waitcnt vmcnt(" #w ")\n\t" \
    "v_readlane_b32 %[t], v" #n ", %[lw]\n\t" \
    "s_bitcmp1_b32 %[win], " #b "\n\t" \
    "s_cselect_b32 %[m], 0, -1\n\t" \
    "s_sub_i32 %[kept], %[kept], %[m]\n\t" \
    "s_and_b32 %[t], %[t], %[m]\n\t" \
    "s_or_b32 %[win], %[win], %[t]\n\t" \
    "v_and_b32 v" #n ", %[m], v" #n "\n\t" \
    "v_or_b32 %[rem], %[rem], v" #n "\n\t"

#define SWIN \
    "s_add_u32 %[lw], %[lw], 1\n\t" \
    "v_readlane_b32 %[t], %[rem], %[lw]\n\t" \
    "s_mov_b32 %[win], %[t]\n\t"

#define ROW_A(M) M(64,0) M(65,1) M(66,2) M(67,3) M(68,4) M(69,5) M(70,6) M(71,7) \
    M(72,8) M(73,9) M(74,10) M(75,11) M(76,12) M(77,13) M(78,14) M(79,15) \
    M(80,16) M(81,17) M(82,18) M(83,19) M(84,20) M(85,21) M(86,22) M(87,23) \
    M(88,24) M(89,25) M(90,26) M(91,27) M(92,28) M(93,29) M(94,30) M(95,31)
#define ROW_B(M) M(96,0) M(97,1) M(98,2) M(99,3) M(100,4) M(101,5) M(102,6) M(103,7) \
    M(104,8) M(105,9) M(106,10) M(107,11) M(108,12) M(109,13) M(110,14) M(111,15) \
    M(112,16) M(113,17) M(114,18) M(115,19) M(116,20) M(117,21) M(118,22) M(119,23) \
    M(120,24) M(121,25) M(122,26) M(123,27) M(124,28) M(125,29) M(126,30) M(127,31)

__global__ __launch_bounds__(256) void nms_scan_select(
    const float* __restrict__ wsBoxes, const float* __restrict__ wsScores,
    const int* __restrict__ wsValid, const uint64_t* __restrict__ mask,
    float* __restrict__ out)
{
    const int n   = blockIdx.x;
    const int tid = threadIdx.x;

    __shared__ __align__(8) unsigned char invb[256];
    __shared__ unsigned int keepw32[64];
    __shared__ int sscan[256];

    unsigned int byte = 0xFFu;
    if (tid < PRE_N / 8) {
        byte = 0u;
        for (int q = 0; q < 8; ++q)
            byte |= (wsValid[n * PRE_N + tid * 8 + q] ? 0u : 1u) << q;
    }
    invb[tid] = (unsigned char)byte;
    __syncthreads();

    if (tid < 64) {
        unsigned int rem = ((const unsigned int*)invb)[tid];
        unsigned long long sbase =
            (unsigned long long)(const void*)(mask + (size_t)n * PRE_N * 32);
        unsigned int voff = (unsigned int)(tid * 4);
        int win_, m_, t_, lw_, kept_, cnt_;

        asm volatile(
            "s_waitcnt vmcnt(0) lgkmcnt(0)\n\t"
            "s_mov_b32 %[kept], 0\n\t"
            "s_mov_b32 %[lw], 0\n\t"
            ROW_A(SL) ROW_B(SL)
            "v_readlane_b32 %[t], %[rem], %[lw]\n\t"
            "s_mov_b32 %[win], %[t]\n\t"
            "s_mov_b32 %[cnt], 30\n\t"
            "Lnms_%=:\n\t"
            ROW_A(SS)
            SWIN
            ROW_B(SS)
            SWIN
            "s_cmp_ge_i32 %[kept], 0x3e8\n\t"
            "s_cbranch_scc1 Lend_%=\n\t"
            "s_sub_u32 %[cnt], %[cnt], 1\n\t"
            "s_cmp_lg_u32 %[cnt], 0\n\t"
            "s_cbranch_scc1 Lnms_%=\n\t"
            SS(64,0) SS(65,1) SS(66,2) SS(67,3) SS(68,4) SS(69,5) SS(70,6) SS(71,7)
            SS(72,8) SS(73,9) SS(74,10) SS(75,11) SS(76,12) SS(77,13) SS(78,14) SS(79,15)
            SN(80,16,63) SN(81,17,62) SN(82,18,61) SN(83,19,60)
            SN(84,20,59) SN(85,21,58) SN(86,22,57) SN(87,23,56)
            SN(88,24,55) SN(89,25,54) SN(90,26,53) SN(91,27,52)
            SN(92,28,51) SN(93,29,50) SN(94,30,49) SN(95,31,48)
            SWIN
            SN(96,0,47) SN(97,1,46) SN(98,2,45) SN(99,3,44)
            SN(100,4,43) SN(101,5,42) SN(102,6,41) SN(103,7,40)
            SN(104,8,39) SN(105,9,38) SN(106,10,37) SN(107,11,36)
            SN(108,12,35) SN(109,13,34) SN(110,14,33) SN(111,15,32)
            SN(112,16,31) SN(113,17,30) SN(114,18,29) SN(115,19,28)
            SN(116,20,27) SN(117,21,26) SN(118,22,25) SN(119,23,24)
            SN(120,24,23) SN(121,25,22) SN(122,26,21) SN(123,27,20)
            SN(124,28,19) SN(125,29,18) SN(126,30,17) SN(127,31,16)
            SWIN
            SN(64,0,15) SN(65,1,14) SN(66,2,13) SN(67,3,12)
            SN(68,4,11) SN(69,5,10) SN(70,6,9) SN(71,7,8)
            SN(72,8,7) SN(73,9,6) SN(74,10,5) SN(75,11,4)
            SN(76,12,3) SN(77,13,2) SN(78,14,1) SN(79,15,0)
            "Lend_%=:\n\t"
            "s_waitcnt vmcnt(0)\n\t"
            : [rem]"+v"(rem), [voff]"+v"(voff),
              [win]"=&s"(win_), [m]"=&s"(m_), [t]"=&s"(t_),
              [lw]"=&s"(lw_), [kept]"=&s"(kept_), [cnt]"=&s"(cnt_)
            : [sbase]"s"(sbase)
            : "scc", "vcc", "memory",
              "v64","v65","v66","v67","v68","v69","v70","v71",
              "v72","v73","v74","v75","v76","v77","v78","v79",
              "v80","v81","v82","v83","v84","v85","v86","v87",
              "v88","v89","v90","v91","v92","v93","v94","v95",
              "v96","v97","v98","v99","v100","v101","v102","v103",
              "v104","v105","v106","v107","v108","v109","v110","v111",
              "v112","v113","v114","v115","v116","v117","v118","v119",
              "v120","v121","v122","v123","v124","v125","v126","v127");

        keepw32[tid] = ~rem;
    }
    __syncthreads();

    int c[8]; const int base8 = tid * 8;
    int lsum = 0;
    for (int q = 0; q < 8; ++q) {
        const int i = base8 + q;
        c[q] = (i < PRE_N) ? (int)((keepw32[i >> 5] >> (i & 31)) & 1u) : 0;
        lsum += c[q];
    }
    sscan[tid] = lsum;
    __syncthreads();
    for (int off = 1; off < 256; off <<= 1) {
        int v = (tid >= off) ? sscan[tid - off] : 0;
        __syncthreads();
        sscan[tid] += v;
        __syncthreads();
    }
    const int excl  = sscan[tid] - lsum;
    const int total = sscan[255];

    float* ob  = out + n * POST_N * 4;
    float* osc = out + NIMG * POST_N * 4 + n * POST_N;
    float* ovd = out + NIMG * POST_N * 5 + n * POST_N;

    for (int i = tid; i < POST_N * 4; i += 256) ob[i] = 0.0f;
    for (int i = tid; i < POST_N; i += 256) osc[i] = 0.0f;
    const int lim = min(total, POST_N);
    for (int i = tid; i < POST_N; i += 256) ovd[i] = (i < lim) ? 1.0f : 0.0f;
    __syncthreads();

    int run = excl;
    for (int q = 0; q < 8; ++q) {
        const int i = base8 + q;
        if (i < PRE_N && c[q]) {
            if (run < POST_N) {
                float4 b = ((const float4*)wsBoxes)[n * PRE_N + i];
                ob[run * 4 + 0] = b.x;
                ob[run * 4 + 1] = b.y;
                ob[run * 4 + 2] = b.z;
                ob[run * 4 + 3] = b.w;
                osc[run] = wsScores[n * PRE_N + i];
            }
            run++;
        }
    }
}

extern "C" void kernel_launch(void* const* d_in, const int* in_sizes, int n_in,
                              void* d_out, int out_size, void* d_ws, size_t ws_size,
                              hipStream_t stream) {
    const float* obj  = (const float*)d_in[0];
    const float* breg = (const float*)d_in[1];
    float* ws        = (float*)d_ws;
    float* wsBoxes   = ws;                      // 64000 floats
    float* wsScores  = ws + 64000;              // 16000 floats
    int*   wsValid   = (int*)(ws + 80000);      // 16000 ints
    uint64_t* wsMask = (uint64_t*)(ws + 96000); // 8*2000*32 u64 = 4 MB
    uint64_t*     candBuf = wsMask;
    unsigned int* candCnt = (unsigned int*)(wsMask + NIMG * CAND_MAX);

    hist_compact<<<NIMG, 1024, 0, stream>>>(obj, candBuf, candCnt);
    rank_decode<<<NIMG * 64, 64, 0, stream>>>(breg, candBuf, candCnt,
                                              wsBoxes, wsScores, wsValid);
    nms_mask<<<NIMG * 32, 512, 0, stream>>>(wsBoxes, wsMask);
    nms_scan_select<<<NIMG, 256, 0, stream>>>(wsBoxes, wsScores, wsValid, wsMask,
                                              (float*)d_out);
}